// Round 1
// baseline (13101.195 us; speedup 1.0000x reference)
//
#include <hip/hip_runtime.h>
#include <math.h>

#define NN 40000
#define NE 500000
#define NEF (NN + NE)
#define NB 512
#define NEG 0.2f

static inline int cdiv(int a, int b) { return (a + b - 1) / b; }

__device__ __forceinline__ void atomicMaxF(float* a, float v) {
  if (v >= 0.f) atomicMax((int*)a, __float_as_int(v));
  else          atomicMin((unsigned int*)a, __float_as_uint(v));
}

// deg[d] += 1, esum[d] += ea[e] over original edges
__global__ void k_deg(const int* __restrict__ ei, const float* __restrict__ ea,
                      float* __restrict__ deg, float* __restrict__ esum) {
  int e = blockIdx.x * 256 + threadIdx.x;
  if (e < NE) {
    int d = ei[NE + e];
    atomicAdd(deg + d, 1.f);
    atomicAdd(esum + d, ea[e]);
  }
}

// loop_attr = deg>0 ? esum/deg : 0   (in place on esum buffer)
__global__ void k_loop(float* __restrict__ lpa, const float* __restrict__ deg) {
  int i = blockIdx.x * 256 + threadIdx.x;
  if (i < NN) {
    float dg = deg[i];
    lpa[i] = dg > 0.f ? lpa[i] / dg : 0.f;
  }
}

// h0[i,0:4] = x[i,0]*w0[:] + b0;  h0[i,4:7] = x[i,1:4]
__global__ void k_h0(const float* __restrict__ x, const float* __restrict__ w0,
                     const float* __restrict__ b0, float* __restrict__ h0) {
  int i = blockIdx.x * 256 + threadIdx.x;
  if (i < NN) {
    float x0 = x[4 * i];
    float* o = h0 + 7 * (size_t)i;
#pragma unroll
    for (int j = 0; j < 4; j++) o[j] = fmaf(x0, w0[j], b0[j]);
    o[4] = x[4 * i + 1];
    o[5] = x[4 * i + 2];
    o[6] = x[4 * i + 3];
  }
}

// xl = h @ wl, xr = h @ wr.  blockDim.x == O, NT nodes per block.
template <int O, int NT>
__global__ __launch_bounds__(O) void k_mm2(const float* __restrict__ h, int F,
                                           const float* __restrict__ wl,
                                           const float* __restrict__ wr,
                                           float* __restrict__ xl, float* __restrict__ xr) {
  const int j = threadIdx.x;
  const long i0 = (long)blockIdx.x * NT;
  float al[NT], ar[NT];
#pragma unroll
  for (int t = 0; t < NT; t++) { al[t] = 0.f; ar[t] = 0.f; }
  for (int k = 0; k < F; k++) {
    const float wlv = wl[k * O + j];
    const float wrv = wr[k * O + j];
#pragma unroll
    for (int t = 0; t < NT; t++) {
      const float hv = h[(i0 + t) * F + k];
      al[t] = fmaf(hv, wlv, al[t]);
      ar[t] = fmaf(hv, wrv, ar[t]);
    }
  }
#pragma unroll
  for (int t = 0; t < NT; t++) {
    xl[(i0 + t) * O + j] = al[t];
    xr[(i0 + t) * O + j] = ar[t];
  }
}

// simple per-(i,j) variant for tiny O (layer 3: O=8)
__global__ void k_mm2_s(const float* __restrict__ h, int F, int O,
                        const float* __restrict__ wl, const float* __restrict__ wr,
                        float* __restrict__ xl, float* __restrict__ xr, int total) {
  int idx = blockIdx.x * 256 + threadIdx.x;
  if (idx >= total) return;
  int i = idx / 8, j = idx & 7;   // O == 8
  float al = 0.f, ar = 0.f;
  const float* hr = h + (size_t)i * F;
  for (int k = 0; k < F; k++) {
    float hv = hr[k];
    al = fmaf(hv, wl[k * O + j], al);
    ar = fmaf(hv, wr[k * O + j], ar);
  }
  xl[idx] = al;
  xr[idx] = ar;
}

__global__ void k_initmd(float* __restrict__ m, float* __restrict__ den, int nh) {
  int i = blockIdx.x * 256 + threadIdx.x;
  if (i < nh) { m[i] = -INFINITY; den[i] = 0.f; }
}

// per edge: logits[e,h] = sum_c att[h,c]*lrelu(xl[src]+xr[dst]+ea*we); atomicMax into m[dst,h]
template <int H, int LOGC>
__global__ void k_logits(const int* __restrict__ ei, const float* __restrict__ ea,
                         const float* __restrict__ lpa, const float* __restrict__ xl,
                         const float* __restrict__ xr, const float* __restrict__ we,
                         const float* __restrict__ att, float* __restrict__ lg_out,
                         float* __restrict__ m) {
  const int O = H << LOGC;
  int e = blockIdx.x * 256 + threadIdx.x;
  if (e >= NEF) return;
  int s, d;
  float eav;
  if (e < NE) { s = ei[e]; d = ei[NE + e]; eav = ea[e]; }
  else        { s = e - NE; d = s; eav = lpa[s]; }
  const float4* xls = (const float4*)(xl + (long)s * O);
  const float4* xrd = (const float4*)(xr + (long)d * O);
  const float4* wv = (const float4*)we;
  const float4* av = (const float4*)att;
  float lg[H];
#pragma unroll
  for (int h = 0; h < H; h++) lg[h] = 0.f;
#pragma unroll
  for (int q = 0; q < (O >> 2); q++) {
    float4 a = xls[q], b = xrd[q], w = wv[q], t = av[q];
    float v, acc = 0.f;
    v = a.x + b.x + eav * w.x; v = v > 0.f ? v : NEG * v; acc = fmaf(v, t.x, acc);
    v = a.y + b.y + eav * w.y; v = v > 0.f ? v : NEG * v; acc = fmaf(v, t.y, acc);
    v = a.z + b.z + eav * w.z; v = v > 0.f ? v : NEG * v; acc = fmaf(v, t.z, acc);
    v = a.w + b.w + eav * w.w; v = v > 0.f ? v : NEG * v; acc = fmaf(v, t.w, acc);
    lg[q >> (LOGC - 2)] += acc;
  }
#pragma unroll
  for (int h = 0; h < H; h++) {
    lg_out[(long)e * H + h] = lg[h];
    atomicMaxF(m + (long)d * H + h, lg[h]);
  }
}

// per edge: ex = exp(logit - m[dst]); den[dst] += ex; num[dst,:] += ex*xl[src,:]
template <int H, int LOGC>
__global__ void k_accum(const int* __restrict__ ei, const float* __restrict__ xl,
                        const float* __restrict__ lg_in, const float* __restrict__ m,
                        float* __restrict__ den, float* __restrict__ num) {
  const int O = H << LOGC;
  int e = blockIdx.x * 256 + threadIdx.x;
  if (e >= NEF) return;
  int s, d;
  if (e < NE) { s = ei[e]; d = ei[NE + e]; }
  else        { s = e - NE; d = s; }
  float ex[H];
#pragma unroll
  for (int h = 0; h < H; h++) {
    ex[h] = expf(lg_in[(long)e * H + h] - m[(long)d * H + h]);
    atomicAdd(den + (long)d * H + h, ex[h]);
  }
  const float4* xls = (const float4*)(xl + (long)s * O);
  float* nd = num + (long)d * O;
#pragma unroll
  for (int q = 0; q < (O >> 2); q++) {
    float4 a = xls[q];
    float exq = ex[q >> (LOGC - 2)];
    atomicAdd(nd + 4 * q + 0, exq * a.x);
    atomicAdd(nd + 4 * q + 1, exq * a.y);
    atomicAdd(nd + 4 * q + 2, exq * a.z);
    atomicAdd(nd + 4 * q + 3, exq * a.w);
  }
}

// h = tanh(num/den + bias), elementwise (in-place safe)
template <int H, int LOGC>
__global__ void k_norm(const float* __restrict__ num, const float* __restrict__ den,
                       const float* __restrict__ bias, float* __restrict__ hout, int total) {
  const int O = H << LOGC;
  int idx = blockIdx.x * 256 + threadIdx.x;
  if (idx >= total) return;
  int i = idx / O, j = idx - i * O;
  float v = num[idx] / den[(long)i * H + (j >> LOGC)] + bias[j];
  hout[idx] = tanhf(v);
}

__global__ void k_pool1(const int* __restrict__ bat, const float* __restrict__ h3,
                        float* __restrict__ sums, float* __restrict__ cnt) {
  int i = blockIdx.x * 256 + threadIdx.x;
  if (i < NN) {
    int b = bat[i];
    atomicAdd(cnt + b, 1.f);
#pragma unroll
    for (int j = 0; j < 8; j++) atomicAdd(sums + b * 8 + j, h3[(size_t)i * 8 + j]);
  }
}

__global__ void k_pool2(const float* __restrict__ sums, const float* __restrict__ cnt,
                        const float* __restrict__ w4, const float* __restrict__ b4,
                        float* __restrict__ out) {
  int b = blockIdx.x * 256 + threadIdx.x;
  if (b < NB) {
    float c = fmaxf(cnt[b], 1.f);
    float acc = b4[0];
#pragma unroll
    for (int j = 0; j < 8; j++) acc = fmaf(sums[b * 8 + j] / c, w4[j], acc);
    out[b] = acc;
  }
}

extern "C" void kernel_launch(void* const* d_in, const int* in_sizes, int n_in,
                              void* d_out, int out_size, void* d_ws, size_t ws_size,
                              hipStream_t stream) {
  const float* x   = (const float*)d_in[0];
  const int*   ei  = (const int*)d_in[1];
  const float* ea  = (const float*)d_in[2];
  const int*   bat = (const int*)d_in[3];
  const float* w0  = (const float*)d_in[4];
  const float* b0  = (const float*)d_in[5];
  const float* wl1 = (const float*)d_in[6];
  const float* wr1 = (const float*)d_in[7];
  const float* we1 = (const float*)d_in[8];
  const float* at1 = (const float*)d_in[9];
  const float* b1  = (const float*)d_in[10];
  const float* wl2 = (const float*)d_in[11];
  const float* wr2 = (const float*)d_in[12];
  const float* we2 = (const float*)d_in[13];
  const float* at2 = (const float*)d_in[14];
  const float* b2  = (const float*)d_in[15];
  const float* wl3 = (const float*)d_in[16];
  const float* wr3 = (const float*)d_in[17];
  const float* we3 = (const float*)d_in[18];
  const float* at3 = (const float*)d_in[19];
  const float* b3  = (const float*)d_in[20];
  const float* w4  = (const float*)d_in[21];
  const float* b4  = (const float*)d_in[22];
  float* out = (float*)d_out;

  float* W = (float*)d_ws;
  size_t o = 0;
  float* deg = W + o; o += NN;
  float* lpa = W + o; o += NN;              // esum -> loop_attr (in place)
  float* h0  = W + o; o += (size_t)7 * NN;
  float* A   = W + o; o += (size_t)256 * NN;  // xl
  float* Bf  = W + o; o += (size_t)256 * NN;  // xr
  float* Cf  = W + o; o += (size_t)256 * NN;  // h input -> numer -> h output (in place)
  float* LG  = W + o; o += (size_t)8 * NEF;
  float* M   = W + o; o += (size_t)8 * NN;
  float* DEN = W + o; o += (size_t)8 * NN;
  float* PS  = W + o; o += (size_t)8 * NB;
  float* PC  = W + o; o += NB;
  (void)ws_size; (void)in_sizes; (void)n_in; (void)out_size;

  // self-loop attrs
  hipMemsetAsync(deg, 0, 2 * NN * sizeof(float), stream);  // deg + esum contiguous
  k_deg<<<cdiv(NE, 256), 256, 0, stream>>>(ei, ea, deg, lpa);
  k_loop<<<cdiv(NN, 256), 256, 0, stream>>>(lpa, deg);
  k_h0<<<cdiv(NN, 256), 256, 0, stream>>>(x, w0, b0, h0);

  // ---- layer 1: F=7 -> H=8, C=32 (O=256) ----
  k_mm2<256, 8><<<NN / 8, 256, 0, stream>>>(h0, 7, wl1, wr1, A, Bf);
  k_initmd<<<cdiv(8 * NN, 256), 256, 0, stream>>>(M, DEN, 8 * NN);
  hipMemsetAsync(Cf, 0, (size_t)256 * NN * sizeof(float), stream);
  k_logits<8, 5><<<cdiv(NEF, 256), 256, 0, stream>>>(ei, ea, lpa, A, Bf, we1, at1, LG, M);
  k_accum<8, 5><<<cdiv(NEF, 256), 256, 0, stream>>>(ei, A, LG, M, DEN, Cf);
  k_norm<8, 5><<<cdiv(256 * NN, 256), 256, 0, stream>>>(Cf, DEN, b1, Cf, 256 * NN);

  // ---- layer 2: F=256 -> H=8, C=16 (O=128) ----
  k_mm2<128, 8><<<NN / 8, 128, 0, stream>>>(Cf, 256, wl2, wr2, A, Bf);
  k_initmd<<<cdiv(8 * NN, 256), 256, 0, stream>>>(M, DEN, 8 * NN);
  hipMemsetAsync(Cf, 0, (size_t)128 * NN * sizeof(float), stream);
  k_logits<8, 4><<<cdiv(NEF, 256), 256, 0, stream>>>(ei, ea, lpa, A, Bf, we2, at2, LG, M);
  k_accum<8, 4><<<cdiv(NEF, 256), 256, 0, stream>>>(ei, A, LG, M, DEN, Cf);
  k_norm<8, 4><<<cdiv(128 * NN, 256), 256, 0, stream>>>(Cf, DEN, b2, Cf, 128 * NN);

  // ---- layer 3: F=128 -> H=1, C=8 (O=8) ----
  k_mm2_s<<<cdiv(8 * NN, 256), 256, 0, stream>>>(Cf, 128, 8, wl3, wr3, A, Bf, 8 * NN);
  k_initmd<<<cdiv(NN, 256), 256, 0, stream>>>(M, DEN, NN);
  hipMemsetAsync(Cf, 0, (size_t)8 * NN * sizeof(float), stream);
  k_logits<1, 3><<<cdiv(NEF, 256), 256, 0, stream>>>(ei, ea, lpa, A, Bf, we3, at3, LG, M);
  k_accum<1, 3><<<cdiv(NEF, 256), 256, 0, stream>>>(ei, A, LG, M, DEN, Cf);
  k_norm<1, 3><<<cdiv(8 * NN, 256), 256, 0, stream>>>(Cf, DEN, b3, Cf, 8 * NN);

  // ---- pooling + head ----
  hipMemsetAsync(PS, 0, 9 * NB * sizeof(float), stream);  // PS + PC contiguous
  k_pool1<<<cdiv(NN, 256), 256, 0, stream>>>(bat, Cf, PS, PC);
  k_pool2<<<cdiv(NB, 256), 256, 0, stream>>>(PS, PC, w4, b4, out);
}

// Round 2
// 698.268 us; speedup vs baseline: 18.7624x; 18.7624x over previous
//
#include <hip/hip_runtime.h>
#include <math.h>

#define NN 40000
#define NE 500000
#define NEF (NN + NE)
#define NB 512
#define NEG 0.2f

static inline int cdiv(int a, int b) { return (a + b - 1) / b; }

// ---------- self-loop attr prep ----------
// degi[d] += 1 (int), esum[d] += ea[e] over original edges
__global__ void k_deg(const int* __restrict__ ei, const float* __restrict__ ea,
                      int* __restrict__ degi, float* __restrict__ esum) {
  int e = blockIdx.x * 256 + threadIdx.x;
  if (e < NE) {
    int d = ei[NE + e];
    atomicAdd(degi + d, 1);
    atomicAdd(esum + d, ea[e]);
  }
}

// lpa = deg>0 ? esum/deg : 0 (in place); then degi += 1 (self-loop) for CSR sizing
__global__ void k_loop(float* __restrict__ lpa, int* __restrict__ degi) {
  int i = blockIdx.x * 256 + threadIdx.x;
  if (i < NN) {
    int dg = degi[i];
    lpa[i] = dg > 0 ? lpa[i] / (float)dg : 0.f;
    degi[i] = dg + 1;
  }
}

// ---------- prefix scan (two-level, 256-wide blocks) ----------
__global__ void k_scan1(const int* __restrict__ degi, int* __restrict__ pre,
                        int* __restrict__ bsum) {
  __shared__ int sh[256];
  int t = threadIdx.x, i = blockIdx.x * 256 + t;
  sh[t] = i < NN ? degi[i] : 0;
  __syncthreads();
  for (int st = 1; st < 256; st <<= 1) {
    int a = t >= st ? sh[t - st] : 0;
    __syncthreads();
    sh[t] += a;
    __syncthreads();
  }
  if (i < NN) pre[i] = sh[t];  // inclusive within block
  if (t == 255) bsum[blockIdx.x] = sh[255];
}

__global__ void k_scan2(int* __restrict__ bsum, int nb) {  // single block, inclusive, in place
  __shared__ int sh[256];
  int t = threadIdx.x;
  sh[t] = t < nb ? bsum[t] : 0;
  __syncthreads();
  for (int st = 1; st < 256; st <<= 1) {
    int a = t >= st ? sh[t - st] : 0;
    __syncthreads();
    sh[t] += a;
    __syncthreads();
  }
  if (t < nb) bsum[t] = sh[t];
}

__global__ void k_scan3(const int* __restrict__ pre, const int* __restrict__ bsum,
                        int* __restrict__ rowptr) {
  int i = blockIdx.x * 256 + threadIdx.x;
  if (i < NN) {
    int off = blockIdx.x > 0 ? bsum[blockIdx.x - 1] : 0;
    rowptr[i + 1] = pre[i] + off;
    if (i == 0) rowptr[0] = 0;
  }
}

// scatter edges into CSR slots (order within a node nondet -> fp jitter ~ulp only)
__global__ void k_fill(const int* __restrict__ ei, const float* __restrict__ ea,
                       const float* __restrict__ lpa, const int* __restrict__ rowptr,
                       int* __restrict__ fillc, int* __restrict__ csrc,
                       float* __restrict__ ceav) {
  int e = blockIdx.x * 256 + threadIdx.x;
  if (e >= NEF) return;
  int s, d;
  float v;
  if (e < NE) { s = ei[e]; d = ei[NE + e]; v = ea[e]; }
  else        { s = e - NE; d = s; v = lpa[s]; }
  int pos = atomicAdd(fillc + d, 1);
  int idx = rowptr[d] + pos;
  csrc[idx] = s;
  ceav[idx] = v;
}

// ---------- node embed ----------
__global__ void k_h0(const float* __restrict__ x, const float* __restrict__ w0,
                     const float* __restrict__ b0, float* __restrict__ h0) {
  int i = blockIdx.x * 256 + threadIdx.x;
  if (i < NN) {
    float x0 = x[4 * i];
    float* o = h0 + 7 * (size_t)i;
#pragma unroll
    for (int j = 0; j < 4; j++) o[j] = fmaf(x0, w0[j], b0[j]);
    o[4] = x[4 * i + 1];
    o[5] = x[4 * i + 2];
    o[6] = x[4 * i + 3];
  }
}

// ---------- dense transforms ----------
template <int O, int NT>
__global__ __launch_bounds__(O) void k_mm2(const float* __restrict__ h, int F,
                                           const float* __restrict__ wl,
                                           const float* __restrict__ wr,
                                           float* __restrict__ xl, float* __restrict__ xr) {
  const int j = threadIdx.x;
  const long i0 = (long)blockIdx.x * NT;
  float al[NT], ar[NT];
#pragma unroll
  for (int t = 0; t < NT; t++) { al[t] = 0.f; ar[t] = 0.f; }
  for (int k = 0; k < F; k++) {
    const float wlv = wl[k * O + j];
    const float wrv = wr[k * O + j];
#pragma unroll
    for (int t = 0; t < NT; t++) {
      const float hv = h[(i0 + t) * F + k];
      al[t] = fmaf(hv, wlv, al[t]);
      ar[t] = fmaf(hv, wrv, ar[t]);
    }
  }
#pragma unroll
  for (int t = 0; t < NT; t++) {
    xl[(i0 + t) * O + j] = al[t];
    xr[(i0 + t) * O + j] = ar[t];
  }
}

__global__ void k_mm2_s(const float* __restrict__ h, int F, int O,
                        const float* __restrict__ wl, const float* __restrict__ wr,
                        float* __restrict__ xl, float* __restrict__ xr, int total) {
  int idx = blockIdx.x * 256 + threadIdx.x;
  if (idx >= total) return;
  int i = idx / 8, j = idx & 7;  // O == 8
  float al = 0.f, ar = 0.f;
  const float* hr = h + (size_t)i * F;
  for (int k = 0; k < F; k++) {
    float hv = hr[k];
    al = fmaf(hv, wl[k * O + j], al);
    ar = fmaf(hv, wr[k * O + j], ar);
  }
  xl[idx] = al;
  xr[idx] = ar;
}

// ---------- fused GATv2 gather layer ----------
// One 64-lane wave per node; lane owns CPL=O/64 contiguous channels.
// Head groups are 8 lanes (32ch/head O=256, 16ch/head O=128).
// Online softmax over the node's incoming CSR edges; epilogue bias+tanh.
template <int O>
__global__ __launch_bounds__(256) void k_gat(const int* __restrict__ rowptr,
                                             const int* __restrict__ csrc,
                                             const float* __restrict__ ceav,
                                             const float* __restrict__ xl,
                                             const float* __restrict__ xr,
                                             const float* __restrict__ we,
                                             const float* __restrict__ att,
                                             const float* __restrict__ bias,
                                             float* __restrict__ hout) {
  constexpr int CPL = O / 64;
  const int lane = threadIdx.x & 63;
  const int node = blockIdx.x * 4 + (threadIdx.x >> 6);
  if (node >= NN) return;
  const int j0 = lane * CPL;
  float xrr[CPL], wev[CPL], attv[CPL], acc[CPL];
#pragma unroll
  for (int c = 0; c < CPL; c++) {
    xrr[c] = xr[(long)node * O + j0 + c];
    wev[c] = we[j0 + c];
    attv[c] = att[j0 + c];
    acc[c] = 0.f;
  }
  float m = -INFINITY, den = 0.f;
  const int kb = rowptr[node], ke = rowptr[node + 1];
  for (int k = kb; k < ke; k++) {
    const int s = csrc[k];
    const float eav = ceav[k];
    float av[CPL];
    if constexpr (CPL == 4) {
      float4 t4 = *(const float4*)(xl + (long)s * O + j0);
      av[0] = t4.x; av[1] = t4.y; av[2] = t4.z; av[3] = t4.w;
    } else {
      float2 t2 = *(const float2*)(xl + (long)s * O + j0);
      av[0] = t2.x; av[1] = t2.y;
    }
    float p = 0.f;
#pragma unroll
    for (int c = 0; c < CPL; c++) {
      float v = av[c] + xrr[c] + eav * wev[c];
      v = v > 0.f ? v : NEG * v;
      p = fmaf(v, attv[c], p);
    }
    // reduce logit over the 8-lane head group
    p += __shfl_xor(p, 1);
    p += __shfl_xor(p, 2);
    p += __shfl_xor(p, 4);
    if (p > m) {
      float sc = expf(m - p);  // exp(-inf)=0 on first edge
      den *= sc;
#pragma unroll
      for (int c = 0; c < CPL; c++) acc[c] *= sc;
      m = p;
    }
    float ex = expf(p - m);
    den += ex;
#pragma unroll
    for (int c = 0; c < CPL; c++) acc[c] = fmaf(ex, av[c], acc[c]);
  }
  float rd = 1.f / den;
#pragma unroll
  for (int c = 0; c < CPL; c++)
    hout[(long)node * O + j0 + c] = tanhf(fmaf(acc[c], rd, bias[j0 + c]));
}

// layer 3: O=8, H=1 -> 8-lane group per node
__global__ __launch_bounds__(256) void k_gat3(const int* __restrict__ rowptr,
                                              const int* __restrict__ csrc,
                                              const float* __restrict__ ceav,
                                              const float* __restrict__ xl,
                                              const float* __restrict__ xr,
                                              const float* __restrict__ we,
                                              const float* __restrict__ att,
                                              const float* __restrict__ bias,
                                              float* __restrict__ hout) {
  const int lane = threadIdx.x & 7;
  const int node = blockIdx.x * 32 + (threadIdx.x >> 3);
  if (node >= NN) return;
  const float xrr = xr[node * 8 + lane];
  const float wev = we[lane];
  const float attv = att[lane];
  float m = -INFINITY, den = 0.f, acc = 0.f;
  const int kb = rowptr[node], ke = rowptr[node + 1];
  for (int k = kb; k < ke; k++) {
    const int s = csrc[k];
    const float eav = ceav[k];
    const float av = xl[s * 8 + lane];
    float v = av + xrr + eav * wev;
    v = v > 0.f ? v : NEG * v;
    float p = v * attv;
    p += __shfl_xor(p, 1);
    p += __shfl_xor(p, 2);
    p += __shfl_xor(p, 4);
    if (p > m) {
      float sc = expf(m - p);
      den *= sc;
      acc *= sc;
      m = p;
    }
    float ex = expf(p - m);
    den += ex;
    acc = fmaf(ex, av, acc);
  }
  hout[node * 8 + lane] = tanhf(acc / den + bias[lane]);
}

// ---------- pooling + head ----------
__global__ void k_pool1(const int* __restrict__ bat, const float* __restrict__ h3,
                        float* __restrict__ sums, float* __restrict__ cnt) {
  int i = blockIdx.x * 256 + threadIdx.x;
  if (i < NN) {
    int b = bat[i];
    atomicAdd(cnt + b, 1.f);
#pragma unroll
    for (int j = 0; j < 8; j++) atomicAdd(sums + b * 8 + j, h3[(size_t)i * 8 + j]);
  }
}

__global__ void k_pool2(const float* __restrict__ sums, const float* __restrict__ cnt,
                        const float* __restrict__ w4, const float* __restrict__ b4,
                        float* __restrict__ out) {
  int b = blockIdx.x * 256 + threadIdx.x;
  if (b < NB) {
    float c = fmaxf(cnt[b], 1.f);
    float acc = b4[0];
#pragma unroll
    for (int j = 0; j < 8; j++) acc = fmaf(sums[b * 8 + j] / c, w4[j], acc);
    out[b] = acc;
  }
}

extern "C" void kernel_launch(void* const* d_in, const int* in_sizes, int n_in,
                              void* d_out, int out_size, void* d_ws, size_t ws_size,
                              hipStream_t stream) {
  const float* x   = (const float*)d_in[0];
  const int*   ei  = (const int*)d_in[1];
  const float* ea  = (const float*)d_in[2];
  const int*   bat = (const int*)d_in[3];
  const float* w0  = (const float*)d_in[4];
  const float* b0  = (const float*)d_in[5];
  const float* wl1 = (const float*)d_in[6];
  const float* wr1 = (const float*)d_in[7];
  const float* we1 = (const float*)d_in[8];
  const float* at1 = (const float*)d_in[9];
  const float* b1  = (const float*)d_in[10];
  const float* wl2 = (const float*)d_in[11];
  const float* wr2 = (const float*)d_in[12];
  const float* we2 = (const float*)d_in[13];
  const float* at2 = (const float*)d_in[14];
  const float* b2  = (const float*)d_in[15];
  const float* wl3 = (const float*)d_in[16];
  const float* wr3 = (const float*)d_in[17];
  const float* we3 = (const float*)d_in[18];
  const float* at3 = (const float*)d_in[19];
  const float* b3  = (const float*)d_in[20];
  const float* w4  = (const float*)d_in[21];
  const float* b4  = (const float*)d_in[22];
  float* out = (float*)d_out;

  char* W = (char*)d_ws;
  size_t o = 0;
  auto alloc = [&](size_t bytes) { void* p = W + o; o += (bytes + 255) & ~(size_t)255; return p; };
  int*   degi   = (int*)alloc(NN * 4);
  int*   fillc  = (int*)alloc(NN * 4);
  float* lpa    = (float*)alloc(NN * 4);  // esum -> loop_attr in place
  int*   rowptr = (int*)alloc((NN + 1) * 4);
  int*   pre    = (int*)alloc(NN * 4);
  int*   bsum   = (int*)alloc(256 * 4);
  int*   csrc   = (int*)alloc((size_t)NEF * 4);
  float* ceav   = (float*)alloc((size_t)NEF * 4);
  float* h0     = (float*)alloc((size_t)7 * NN * 4);
  float* A      = (float*)alloc((size_t)256 * NN * 4);  // xl
  float* Bf     = (float*)alloc((size_t)256 * NN * 4);  // xr
  float* Cf     = (float*)alloc((size_t)256 * NN * 4);  // h (in/out per layer)
  float* PS     = (float*)alloc(8 * NB * 4);
  float* PC     = (float*)alloc(NB * 4);
  (void)ws_size; (void)in_sizes; (void)n_in; (void)out_size;

  const int NBLK = cdiv(NN, 256);  // 157 scan blocks

  // ---- CSR build (once; shared by all 3 layers) ----
  hipMemsetAsync(degi, 0, NN * 4, stream);
  hipMemsetAsync(fillc, 0, NN * 4, stream);
  hipMemsetAsync(lpa, 0, NN * 4, stream);
  k_deg<<<cdiv(NE, 256), 256, 0, stream>>>(ei, ea, degi, lpa);
  k_loop<<<NBLK, 256, 0, stream>>>(lpa, degi);
  k_scan1<<<NBLK, 256, 0, stream>>>(degi, pre, bsum);
  k_scan2<<<1, 256, 0, stream>>>(bsum, NBLK);
  k_scan3<<<NBLK, 256, 0, stream>>>(pre, bsum, rowptr);
  k_fill<<<cdiv(NEF, 256), 256, 0, stream>>>(ei, ea, lpa, rowptr, fillc, csrc, ceav);

  k_h0<<<NBLK, 256, 0, stream>>>(x, w0, b0, h0);

  // ---- layer 1: F=7 -> H=8,C=32 (O=256) ----
  k_mm2<256, 8><<<NN / 8, 256, 0, stream>>>(h0, 7, wl1, wr1, A, Bf);
  k_gat<256><<<cdiv(NN, 4), 256, 0, stream>>>(rowptr, csrc, ceav, A, Bf, we1, at1, b1, Cf);

  // ---- layer 2: F=256 -> H=8,C=16 (O=128) ----
  k_mm2<128, 8><<<NN / 8, 128, 0, stream>>>(Cf, 256, wl2, wr2, A, Bf);
  k_gat<128><<<cdiv(NN, 4), 256, 0, stream>>>(rowptr, csrc, ceav, A, Bf, we2, at2, b2, Cf);

  // ---- layer 3: F=128 -> H=1,C=8 (O=8) ----
  k_mm2_s<<<cdiv(8 * NN, 256), 256, 0, stream>>>(Cf, 128, 8, wl3, wr3, A, Bf, 8 * NN);
  k_gat3<<<cdiv(NN, 32), 256, 0, stream>>>(rowptr, csrc, ceav, A, Bf, we3, at3, b3, Cf);

  // ---- pooling + head ----
  hipMemsetAsync(PS, 0, 9 * NB * 4, stream);  // PS + PC contiguous
  k_pool1<<<NBLK, 256, 0, stream>>>(bat, Cf, PS, PC);
  k_pool2<<<cdiv(NB, 256), 256, 0, stream>>>(PS, PC, w4, b4, out);
}

// Round 3
// 464.283 us; speedup vs baseline: 28.2181x; 1.5040x over previous
//
#include <hip/hip_runtime.h>
#include <math.h>

#define NN 40000
#define NNP 40064              // NN padded to 128 for MFMA GEMM
#define NE 500000
#define NEF (NN + NE)
#define NB 512
#define NEG 0.2f

static inline int cdiv(int a, int b) { return (a + b - 1) / b; }

typedef __attribute__((ext_vector_type(8))) short short8;
typedef __attribute__((ext_vector_type(4))) float f32x4;

__device__ __forceinline__ unsigned short f2bf(float f) {
  unsigned u = __float_as_uint(f);
  unsigned r = (u + 0x7fffu + ((u >> 16) & 1u)) >> 16;
  return (unsigned short)r;
}
__device__ __forceinline__ float bf2f(unsigned short h) {
  return __uint_as_float((unsigned)h << 16);
}

// ---------- self-loop attr prep ----------
__global__ void k_deg(const int* __restrict__ ei, const float* __restrict__ ea,
                      int* __restrict__ degi, float* __restrict__ esum) {
  int e = blockIdx.x * 256 + threadIdx.x;
  if (e < NE) {
    int d = ei[NE + e];
    atomicAdd(degi + d, 1);
    atomicAdd(esum + d, ea[e]);
  }
}

__global__ void k_loop(float* __restrict__ lpa, int* __restrict__ degi) {
  int i = blockIdx.x * 256 + threadIdx.x;
  if (i < NN) {
    int dg = degi[i];
    lpa[i] = dg > 0 ? lpa[i] / (float)dg : 0.f;
    degi[i] = dg + 1;
  }
}

// ---------- prefix scan ----------
__global__ void k_scan1(const int* __restrict__ degi, int* __restrict__ pre,
                        int* __restrict__ bsum) {
  __shared__ int sh[256];
  int t = threadIdx.x, i = blockIdx.x * 256 + t;
  sh[t] = i < NN ? degi[i] : 0;
  __syncthreads();
  for (int st = 1; st < 256; st <<= 1) {
    int a = t >= st ? sh[t - st] : 0;
    __syncthreads();
    sh[t] += a;
    __syncthreads();
  }
  if (i < NN) pre[i] = sh[t];
  if (t == 255) bsum[blockIdx.x] = sh[255];
}

__global__ void k_scan2(int* __restrict__ bsum, int nb) {
  __shared__ int sh[256];
  int t = threadIdx.x;
  sh[t] = t < nb ? bsum[t] : 0;
  __syncthreads();
  for (int st = 1; st < 256; st <<= 1) {
    int a = t >= st ? sh[t - st] : 0;
    __syncthreads();
    sh[t] += a;
    __syncthreads();
  }
  if (t < nb) bsum[t] = sh[t];
}

__global__ void k_scan3(const int* __restrict__ pre, const int* __restrict__ bsum,
                        int* __restrict__ rowptr) {
  int i = blockIdx.x * 256 + threadIdx.x;
  if (i < NN) {
    int off = blockIdx.x > 0 ? bsum[blockIdx.x - 1] : 0;
    rowptr[i + 1] = pre[i] + off;
    if (i == 0) rowptr[0] = 0;
  }
}

__global__ void k_fill(const int* __restrict__ ei, const float* __restrict__ ea,
                       const float* __restrict__ lpa, const int* __restrict__ rowptr,
                       int* __restrict__ fillc, int* __restrict__ csrc,
                       float* __restrict__ ceav) {
  int e = blockIdx.x * 256 + threadIdx.x;
  if (e >= NEF) return;
  int s, d;
  float v;
  if (e < NE) { s = ei[e]; d = ei[NE + e]; v = ea[e]; }
  else        { s = e - NE; d = s; v = lpa[s]; }
  int pos = atomicAdd(fillc + d, 1);
  int idx = rowptr[d] + pos;
  csrc[idx] = s;
  ceav[idx] = v;
}

// ---------- node embed ----------
__global__ void k_h0(const float* __restrict__ x, const float* __restrict__ w0,
                     const float* __restrict__ b0, float* __restrict__ h0) {
  int i = blockIdx.x * 256 + threadIdx.x;
  if (i < NN) {
    float x0 = x[4 * i];
    float* o = h0 + 7 * (size_t)i;
#pragma unroll
    for (int j = 0; j < 4; j++) o[j] = fmaf(x0, w0[j], b0[j]);
    o[4] = x[4 * i + 1];
    o[5] = x[4 * i + 2];
    o[6] = x[4 * i + 3];
  }
}

// ---------- dense transforms (vector, layers 1 & 3) ----------
template <int O, int NT>
__global__ __launch_bounds__(O) void k_mm2(const float* __restrict__ h, int F,
                                           const float* __restrict__ wl,
                                           const float* __restrict__ wr,
                                           float* __restrict__ xl, float* __restrict__ xr) {
  const int j = threadIdx.x;
  const long i0 = (long)blockIdx.x * NT;
  float al[NT], ar[NT];
#pragma unroll
  for (int t = 0; t < NT; t++) { al[t] = 0.f; ar[t] = 0.f; }
  for (int k = 0; k < F; k++) {
    const float wlv = wl[k * O + j];
    const float wrv = wr[k * O + j];
#pragma unroll
    for (int t = 0; t < NT; t++) {
      const float hv = h[(i0 + t) * F + k];
      al[t] = fmaf(hv, wlv, al[t]);
      ar[t] = fmaf(hv, wrv, ar[t]);
    }
  }
#pragma unroll
  for (int t = 0; t < NT; t++) {
    xl[(i0 + t) * O + j] = al[t];
    xr[(i0 + t) * O + j] = ar[t];
  }
}

__global__ void k_mm2_s(const float* __restrict__ h, int F, int O,
                        const float* __restrict__ wl, const float* __restrict__ wr,
                        float* __restrict__ xl, float* __restrict__ xr, int total) {
  int idx = blockIdx.x * 256 + threadIdx.x;
  if (idx >= total) return;
  int i = idx / 8, j = idx & 7;  // O == 8
  float al = 0.f, ar = 0.f;
  const float* hr = h + (size_t)i * F;
  for (int k = 0; k < F; k++) {
    float hv = hr[k];
    al = fmaf(hv, wl[k * O + j], al);
    ar = fmaf(hv, wr[k * O + j], ar);
  }
  xl[idx] = al;
  xr[idx] = ar;
}

// ---------- layer-2 MFMA path: split h into bf16 hi/lo ----------
// 8 elems/thread; pad rows (i >= NN) are zero-filled every call.
__global__ void k_split(const float* __restrict__ h, short* __restrict__ ah,
                        short* __restrict__ al) {
  long idx = (long)(blockIdx.x * 256 + threadIdx.x);
  if (idx >= (long)NNP * 256 / 8) return;
  long base = idx * 8;
  int i = (int)(base >> 8);
  short hi[8], lo[8];
  if (i < NN) {
    const float4* p = (const float4*)(h + base);
    float4 v0 = p[0], v1 = p[1];
    float vv[8] = {v0.x, v0.y, v0.z, v0.w, v1.x, v1.y, v1.z, v1.w};
#pragma unroll
    for (int j = 0; j < 8; j++) {
      unsigned short hb = f2bf(vv[j]);
      hi[j] = (short)hb;
      lo[j] = (short)f2bf(vv[j] - bf2f(hb));
    }
  } else {
#pragma unroll
    for (int j = 0; j < 8; j++) { hi[j] = 0; lo[j] = 0; }
  }
  *(short8*)(ah + base) = *(short8*)hi;
  *(short8*)(al + base) = *(short8*)lo;
}

// W = [wl2 | wr2] (256x256), transposed to [n][k], split hi/lo.
__global__ void k_wsplit(const float* __restrict__ wl, const float* __restrict__ wr,
                         short* __restrict__ bh, short* __restrict__ bl) {
  int id = blockIdx.x * 256 + threadIdx.x;  // 65536
  int n = id >> 8, k = id & 255;
  float w = n < 128 ? wl[k * 128 + n] : wr[k * 128 + n - 128];
  unsigned short hb = f2bf(w);
  bh[n * 256 + k] = (short)hb;
  bl[n * 256 + k] = (short)f2bf(w - bf2f(hb));
}

// C[m,n] = sum_k a[m,k]*w[k,n], K=256, via 3 bf16 passes: hi*hi + hi*lo + lo*hi.
// BM=128, BN=64, BK=32; 4 waves, wave tile 64x32 (4x2 frags of 16x16x32).
// LDS rows padded to 40 shorts (80 B) -> ds_read_b128 ~2-way conflicts (free).
__global__ __launch_bounds__(256) void k_gemm2(const short* __restrict__ ah,
                                               const short* __restrict__ al,
                                               const short* __restrict__ bh,
                                               const short* __restrict__ bl,
                                               float* __restrict__ xl,
                                               float* __restrict__ xr) {
  __shared__ short sA[128 * 40];
  __shared__ short sB[64 * 40];
  const int tid = threadIdx.x;
  const int bm = blockIdx.x >> 2, bn = blockIdx.x & 3;
  const int wid = tid >> 6, lane = tid & 63;
  const int wr = wid >> 1, wc = wid & 1;
  const int l15 = lane & 15, lhi = lane >> 4;
  const int srow = tid >> 2;          // 0..63 staging row
  const int kq = (tid & 3) * 8;       // staging k-offset (shorts)
  f32x4 acc[4][2];
#pragma unroll
  for (int a = 0; a < 4; a++)
#pragma unroll
    for (int b = 0; b < 2; b++) acc[a][b] = (f32x4)(0.f);

  for (int p = 0; p < 3; p++) {
    const short* As = p < 2 ? ah : al;
    const short* Bs = p == 1 ? bl : bh;
#pragma unroll 1
    for (int st = 0; st < 8; st++) {
      const int k0 = st * 32;
      short8 va0 = *(const short8*)(As + ((long)(bm * 128 + srow) * 256 + k0 + kq));
      short8 va1 = *(const short8*)(As + ((long)(bm * 128 + 64 + srow) * 256 + k0 + kq));
      short8 vb  = *(const short8*)(Bs + ((long)(bn * 64 + srow) * 256 + k0 + kq));
      __syncthreads();  // previous step's frag reads done
      *(short8*)&sA[srow * 40 + kq] = va0;
      *(short8*)&sA[(64 + srow) * 40 + kq] = va1;
      *(short8*)&sB[srow * 40 + kq] = vb;
      __syncthreads();
      short8 bfr[2];
#pragma unroll
      for (int fn = 0; fn < 2; fn++)
        bfr[fn] = *(const short8*)&sB[(wc * 32 + fn * 16 + l15) * 40 + lhi * 8];
#pragma unroll
      for (int fm = 0; fm < 4; fm++) {
        short8 afr = *(const short8*)&sA[(wr * 64 + fm * 16 + l15) * 40 + lhi * 8];
        acc[fm][0] = __builtin_amdgcn_mfma_f32_16x16x32_bf16(afr, bfr[0], acc[fm][0], 0, 0, 0);
        acc[fm][1] = __builtin_amdgcn_mfma_f32_16x16x32_bf16(afr, bfr[1], acc[fm][1], 0, 0, 0);
      }
    }
  }
#pragma unroll
  for (int fm = 0; fm < 4; fm++)
#pragma unroll
    for (int fn = 0; fn < 2; fn++) {
      int col = bn * 64 + wc * 32 + fn * 16 + l15;
      float* dst = col < 128 ? xl + col : xr + (col - 128);
#pragma unroll
      for (int j = 0; j < 4; j++) {
        int row = bm * 128 + wr * 64 + fm * 16 + lhi * 4 + j;
        dst[(long)row * 128] = acc[fm][fn][j];
      }
    }
}

// ---------- fused GATv2 gather layer ----------
template <int O>
__global__ __launch_bounds__(256) void k_gat(const int* __restrict__ rowptr,
                                             const int* __restrict__ csrc,
                                             const float* __restrict__ ceav,
                                             const float* __restrict__ xl,
                                             const float* __restrict__ xr,
                                             const float* __restrict__ we,
                                             const float* __restrict__ att,
                                             const float* __restrict__ bias,
                                             float* __restrict__ hout) {
  constexpr int CPL = O / 64;
  const int lane = threadIdx.x & 63;
  const int node = blockIdx.x * 4 + (threadIdx.x >> 6);
  if (node >= NN) return;
  const int j0 = lane * CPL;
  float xrr[CPL], wev[CPL], attv[CPL], acc[CPL];
#pragma unroll
  for (int c = 0; c < CPL; c++) {
    xrr[c] = xr[(long)node * O + j0 + c];
    wev[c] = we[j0 + c];
    attv[c] = att[j0 + c];
    acc[c] = 0.f;
  }
  float m = -INFINITY, den = 0.f;
  const int kb = rowptr[node], ke = rowptr[node + 1];
  for (int k = kb; k < ke; k++) {
    const int s = csrc[k];
    const float eav = ceav[k];
    float av[CPL];
    if constexpr (CPL == 4) {
      float4 t4 = *(const float4*)(xl + (long)s * O + j0);
      av[0] = t4.x; av[1] = t4.y; av[2] = t4.z; av[3] = t4.w;
    } else {
      float2 t2 = *(const float2*)(xl + (long)s * O + j0);
      av[0] = t2.x; av[1] = t2.y;
    }
    float p = 0.f;
#pragma unroll
    for (int c = 0; c < CPL; c++) {
      float v = av[c] + xrr[c] + eav * wev[c];
      v = v > 0.f ? v : NEG * v;
      p = fmaf(v, attv[c], p);
    }
    p += __shfl_xor(p, 1);
    p += __shfl_xor(p, 2);
    p += __shfl_xor(p, 4);
    if (p > m) {
      float sc = expf(m - p);  // exp(-inf)=0 on first edge
      den *= sc;
#pragma unroll
      for (int c = 0; c < CPL; c++) acc[c] *= sc;
      m = p;
    }
    float ex = expf(p - m);
    den += ex;
#pragma unroll
    for (int c = 0; c < CPL; c++) acc[c] = fmaf(ex, av[c], acc[c]);
  }
  float rd = 1.f / den;
#pragma unroll
  for (int c = 0; c < CPL; c++)
    hout[(long)node * O + j0 + c] = tanhf(fmaf(acc[c], rd, bias[j0 + c]));
}

__global__ __launch_bounds__(256) void k_gat3(const int* __restrict__ rowptr,
                                              const int* __restrict__ csrc,
                                              const float* __restrict__ ceav,
                                              const float* __restrict__ xl,
                                              const float* __restrict__ xr,
                                              const float* __restrict__ we,
                                              const float* __restrict__ att,
                                              const float* __restrict__ bias,
                                              float* __restrict__ hout) {
  const int lane = threadIdx.x & 7;
  const int node = blockIdx.x * 32 + (threadIdx.x >> 3);
  if (node >= NN) return;
  const float xrr = xr[node * 8 + lane];
  const float wev = we[lane];
  const float attv = att[lane];
  float m = -INFINITY, den = 0.f, acc = 0.f;
  const int kb = rowptr[node], ke = rowptr[node + 1];
  for (int k = kb; k < ke; k++) {
    const int s = csrc[k];
    const float eav = ceav[k];
    const float av = xl[s * 8 + lane];
    float v = av + xrr + eav * wev;
    v = v > 0.f ? v : NEG * v;
    float p = v * attv;
    p += __shfl_xor(p, 1);
    p += __shfl_xor(p, 2);
    p += __shfl_xor(p, 4);
    if (p > m) {
      float sc = expf(m - p);
      den *= sc;
      acc *= sc;
      m = p;
    }
    float ex = expf(p - m);
    den += ex;
    acc = fmaf(ex, av, acc);
  }
  hout[node * 8 + lane] = tanhf(acc / den + bias[lane]);
}

// ---------- pooling + head ----------
__global__ void k_pool1(const int* __restrict__ bat, const float* __restrict__ h3,
                        float* __restrict__ sums, float* __restrict__ cnt) {
  int i = blockIdx.x * 256 + threadIdx.x;
  if (i < NN) {
    int b = bat[i];
    atomicAdd(cnt + b, 1.f);
#pragma unroll
    for (int j = 0; j < 8; j++) atomicAdd(sums + b * 8 + j, h3[(size_t)i * 8 + j]);
  }
}

__global__ void k_pool2(const float* __restrict__ sums, const float* __restrict__ cnt,
                        const float* __restrict__ w4, const float* __restrict__ b4,
                        float* __restrict__ out) {
  int b = blockIdx.x * 256 + threadIdx.x;
  if (b < NB) {
    float c = fmaxf(cnt[b], 1.f);
    float acc = b4[0];
#pragma unroll
    for (int j = 0; j < 8; j++) acc = fmaf(sums[b * 8 + j] / c, w4[j], acc);
    out[b] = acc;
  }
}

extern "C" void kernel_launch(void* const* d_in, const int* in_sizes, int n_in,
                              void* d_out, int out_size, void* d_ws, size_t ws_size,
                              hipStream_t stream) {
  const float* x   = (const float*)d_in[0];
  const int*   ei  = (const int*)d_in[1];
  const float* ea  = (const float*)d_in[2];
  const int*   bat = (const int*)d_in[3];
  const float* w0  = (const float*)d_in[4];
  const float* b0  = (const float*)d_in[5];
  const float* wl1 = (const float*)d_in[6];
  const float* wr1 = (const float*)d_in[7];
  const float* we1 = (const float*)d_in[8];
  const float* at1 = (const float*)d_in[9];
  const float* b1  = (const float*)d_in[10];
  const float* wl2 = (const float*)d_in[11];
  const float* wr2 = (const float*)d_in[12];
  const float* we2 = (const float*)d_in[13];
  const float* at2 = (const float*)d_in[14];
  const float* b2  = (const float*)d_in[15];
  const float* wl3 = (const float*)d_in[16];
  const float* wr3 = (const float*)d_in[17];
  const float* we3 = (const float*)d_in[18];
  const float* at3 = (const float*)d_in[19];
  const float* b3  = (const float*)d_in[20];
  const float* w4  = (const float*)d_in[21];
  const float* b4  = (const float*)d_in[22];
  float* out = (float*)d_out;

  char* W = (char*)d_ws;
  size_t o = 0;
  auto alloc = [&](size_t bytes) { void* p = W + o; o += (bytes + 255) & ~(size_t)255; return p; };
  int*   degi   = (int*)alloc(NN * 4);
  int*   fillc  = (int*)alloc(NN * 4);
  float* lpa    = (float*)alloc(NN * 4);
  int*   rowptr = (int*)alloc((NN + 1) * 4);
  int*   pre    = (int*)alloc(NN * 4);
  int*   bsum   = (int*)alloc(256 * 4);
  int*   csrc   = (int*)alloc((size_t)NEF * 4);
  float* ceav   = (float*)alloc((size_t)NEF * 4);
  float* h0     = (float*)alloc((size_t)7 * NN * 4);
  float* A      = (float*)alloc((size_t)256 * NN * 4);  // xl
  float* Bf     = (float*)alloc((size_t)256 * NN * 4);  // xr
  float* Cf     = (float*)alloc((size_t)256 * NN * 4);  // h (in/out per layer)
  short* Ah     = (short*)alloc((size_t)NNP * 256 * 2);
  short* Al     = (short*)alloc((size_t)NNP * 256 * 2);
  short* Bh     = (short*)alloc((size_t)256 * 256 * 2);
  short* Bl     = (short*)alloc((size_t)256 * 256 * 2);
  float* PS     = (float*)alloc(8 * NB * 4);
  float* PC     = (float*)alloc(NB * 4);
  (void)ws_size; (void)in_sizes; (void)n_in; (void)out_size;

  const int NBLK = cdiv(NN, 256);

  // ---- CSR build ----
  hipMemsetAsync(degi, 0, NN * 4, stream);
  hipMemsetAsync(fillc, 0, NN * 4, stream);
  hipMemsetAsync(lpa, 0, NN * 4, stream);
  k_deg<<<cdiv(NE, 256), 256, 0, stream>>>(ei, ea, degi, lpa);
  k_loop<<<NBLK, 256, 0, stream>>>(lpa, degi);
  k_scan1<<<NBLK, 256, 0, stream>>>(degi, pre, bsum);
  k_scan2<<<1, 256, 0, stream>>>(bsum, NBLK);
  k_scan3<<<NBLK, 256, 0, stream>>>(pre, bsum, rowptr);
  k_fill<<<cdiv(NEF, 256), 256, 0, stream>>>(ei, ea, lpa, rowptr, fillc, csrc, ceav);

  k_h0<<<NBLK, 256, 0, stream>>>(x, w0, b0, h0);

  // ---- layer 1: F=7 -> H=8,C=32 (O=256) ----
  k_mm2<256, 8><<<NN / 8, 256, 0, stream>>>(h0, 7, wl1, wr1, A, Bf);
  k_gat<256><<<cdiv(NN, 4), 256, 0, stream>>>(rowptr, csrc, ceav, A, Bf, we1, at1, b1, Cf);

  // ---- layer 2: F=256 -> H=8,C=16 (O=128), MFMA hi/lo split ----
  k_split<<<cdiv(NNP * 256 / 8, 256), 256, 0, stream>>>(Cf, Ah, Al);
  k_wsplit<<<256, 256, 0, stream>>>(wl2, wr2, Bh, Bl);
  k_gemm2<<<(NNP / 128) * 4, 256, 0, stream>>>(Ah, Al, Bh, Bl, A, Bf);
  k_gat<128><<<cdiv(NN, 4), 256, 0, stream>>>(rowptr, csrc, ceav, A, Bf, we2, at2, b2, Cf);

  // ---- layer 3: F=128 -> H=1,C=8 (O=8) ----
  k_mm2_s<<<cdiv(8 * NN, 256), 256, 0, stream>>>(Cf, 128, 8, wl3, wr3, A, Bf, 8 * NN);
  k_gat3<<<cdiv(NN, 32), 256, 0, stream>>>(rowptr, csrc, ceav, A, Bf, we3, at3, b3, Cf);

  // ---- pooling + head ----
  hipMemsetAsync(PS, 0, 9 * NB * 4, stream);
  k_pool1<<<NBLK, 256, 0, stream>>>(bat, Cf, PS, PC);
  k_pool2<<<cdiv(NB, 256), 256, 0, stream>>>(PS, PC, w4, b4, out);
}

// Round 4
// 427.324 us; speedup vs baseline: 30.6587x; 1.0865x over previous
//
#include <hip/hip_runtime.h>
#include <math.h>

#define NN 40000
#define NNP 40064              // NN padded to 128 for MFMA GEMM
#define NE 500000
#define NEF (NN + NE)
#define NB 512
#define NEG 0.2f

static inline int cdiv(int a, int b) { return (a + b - 1) / b; }

typedef __attribute__((ext_vector_type(8))) short short8;
typedef __attribute__((ext_vector_type(4))) short short4v;
typedef __attribute__((ext_vector_type(4))) float f32x4;
typedef __attribute__((ext_vector_type(2))) _Float16 half2v;

__device__ __forceinline__ unsigned short f2bf(float f) {
  unsigned u = __float_as_uint(f);
  unsigned r = (u + 0x7fffu + ((u >> 16) & 1u)) >> 16;
  return (unsigned short)r;
}
__device__ __forceinline__ float bf2f(unsigned short h) {
  return __uint_as_float((unsigned)h << 16);
}

// ---------- self-loop attr prep ----------
__global__ void k_deg(const int* __restrict__ ei, const float* __restrict__ ea,
                      int* __restrict__ degi, float* __restrict__ esum) {
  int e = blockIdx.x * 256 + threadIdx.x;
  if (e < NE) {
    int d = ei[NE + e];
    atomicAdd(degi + d, 1);
    atomicAdd(esum + d, ea[e]);
  }
}

__global__ void k_loop(float* __restrict__ lpa, int* __restrict__ degi) {
  int i = blockIdx.x * 256 + threadIdx.x;
  if (i < NN) {
    int dg = degi[i];
    lpa[i] = dg > 0 ? lpa[i] / (float)dg : 0.f;
    degi[i] = dg + 1;
  }
}

// ---------- prefix scan ----------
__global__ void k_scan1(const int* __restrict__ degi, int* __restrict__ pre,
                        int* __restrict__ bsum) {
  __shared__ int sh[256];
  int t = threadIdx.x, i = blockIdx.x * 256 + t;
  sh[t] = i < NN ? degi[i] : 0;
  __syncthreads();
  for (int st = 1; st < 256; st <<= 1) {
    int a = t >= st ? sh[t - st] : 0;
    __syncthreads();
    sh[t] += a;
    __syncthreads();
  }
  if (i < NN) pre[i] = sh[t];
  if (t == 255) bsum[blockIdx.x] = sh[255];
}

__global__ void k_scan2(int* __restrict__ bsum, int nb) {
  __shared__ int sh[256];
  int t = threadIdx.x;
  sh[t] = t < nb ? bsum[t] : 0;
  __syncthreads();
  for (int st = 1; st < 256; st <<= 1) {
    int a = t >= st ? sh[t - st] : 0;
    __syncthreads();
    sh[t] += a;
    __syncthreads();
  }
  if (t < nb) bsum[t] = sh[t];
}

__global__ void k_scan3(const int* __restrict__ pre, const int* __restrict__ bsum,
                        int* __restrict__ rowptr) {
  int i = blockIdx.x * 256 + threadIdx.x;
  if (i < NN) {
    int off = blockIdx.x > 0 ? bsum[blockIdx.x - 1] : 0;
    rowptr[i + 1] = pre[i] + off;
    if (i == 0) rowptr[0] = 0;
  }
}

__global__ void k_fill(const int* __restrict__ ei, const float* __restrict__ ea,
                       const float* __restrict__ lpa, const int* __restrict__ rowptr,
                       int* __restrict__ fillc, int* __restrict__ csrc,
                       float* __restrict__ ceav) {
  int e = blockIdx.x * 256 + threadIdx.x;
  if (e >= NEF) return;
  int s, d;
  float v;
  if (e < NE) { s = ei[e]; d = ei[NE + e]; v = ea[e]; }
  else        { s = e - NE; d = s; v = lpa[s]; }
  int pos = atomicAdd(fillc + d, 1);
  int idx = rowptr[d] + pos;
  csrc[idx] = s;
  ceav[idx] = v;
}

// ---------- node embed (padded to stride 8, [7]=0) ----------
__global__ void k_h0(const float* __restrict__ x, const float* __restrict__ w0,
                     const float* __restrict__ b0, float* __restrict__ h0p) {
  int i = blockIdx.x * 256 + threadIdx.x;
  if (i < NN) {
    float x0 = x[4 * i];
    float* o = h0p + 8 * (size_t)i;
#pragma unroll
    for (int j = 0; j < 4; j++) o[j] = fmaf(x0, w0[j], b0[j]);
    o[4] = x[4 * i + 1];
    o[5] = x[4 * i + 2];
    o[6] = x[4 * i + 3];
    o[7] = 0.f;
  }
}

// ---------- layer 1 fully fused: xl/xr computed on the fly from h0 (F=7) ----------
// wave per node, lane owns 4 channels of O=256. Output: bf16 hi/lo split of h1.
__global__ __launch_bounds__(256) void k_gat1(const int* __restrict__ rowptr,
                                              const int* __restrict__ csrc,
                                              const float* __restrict__ ceav,
                                              const float* __restrict__ h0p,
                                              const float* __restrict__ wl,
                                              const float* __restrict__ wr,
                                              const float* __restrict__ we,
                                              const float* __restrict__ att,
                                              const float* __restrict__ bias,
                                              short* __restrict__ ah,
                                              short* __restrict__ al) {
  const int lane = threadIdx.x & 63;
  const int node = blockIdx.x * 4 + (threadIdx.x >> 6);
  if (node >= NN) return;
  const int j0 = lane * 4;

  float4 wev = *(const float4*)(we + j0);
  float4 attv = *(const float4*)(att + j0);
  float wlr[7][4];
#pragma unroll
  for (int k = 0; k < 7; k++) {
    float4 t = *(const float4*)(wl + k * 256 + j0);
    wlr[k][0] = t.x; wlr[k][1] = t.y; wlr[k][2] = t.z; wlr[k][3] = t.w;
  }
  // xr for this node (wr weights live only here)
  float xrr[4] = {0.f, 0.f, 0.f, 0.f};
  {
    float4 hd0 = *(const float4*)(h0p + (size_t)node * 8);
    float4 hd1 = *(const float4*)(h0p + (size_t)node * 8 + 4);
    float hn[7] = {hd0.x, hd0.y, hd0.z, hd0.w, hd1.x, hd1.y, hd1.z};
#pragma unroll
    for (int k = 0; k < 7; k++) {
      float4 t = *(const float4*)(wr + k * 256 + j0);
      xrr[0] = fmaf(hn[k], t.x, xrr[0]);
      xrr[1] = fmaf(hn[k], t.y, xrr[1]);
      xrr[2] = fmaf(hn[k], t.z, xrr[2]);
      xrr[3] = fmaf(hn[k], t.w, xrr[3]);
    }
  }

  float m = -INFINITY, den = 0.f;
  float acc[4] = {0.f, 0.f, 0.f, 0.f};
  const int kb = rowptr[node], ke = rowptr[node + 1];
  for (int k = kb; k < ke; k++) {
    const int s = csrc[k];
    const float eav = ceav[k];
    float4 a0 = *(const float4*)(h0p + (size_t)s * 8);
    float4 a1 = *(const float4*)(h0p + (size_t)s * 8 + 4);
    float hs[7] = {a0.x, a0.y, a0.z, a0.w, a1.x, a1.y, a1.z};
    float xls[4] = {0.f, 0.f, 0.f, 0.f};
#pragma unroll
    for (int kk = 0; kk < 7; kk++) {
      xls[0] = fmaf(hs[kk], wlr[kk][0], xls[0]);
      xls[1] = fmaf(hs[kk], wlr[kk][1], xls[1]);
      xls[2] = fmaf(hs[kk], wlr[kk][2], xls[2]);
      xls[3] = fmaf(hs[kk], wlr[kk][3], xls[3]);
    }
    float p = 0.f;
    {
      float v;
      v = xls[0] + fmaf(eav, wev.x, xrr[0]); v = v > 0.f ? v : NEG * v; p = fmaf(v, attv.x, p);
      v = xls[1] + fmaf(eav, wev.y, xrr[1]); v = v > 0.f ? v : NEG * v; p = fmaf(v, attv.y, p);
      v = xls[2] + fmaf(eav, wev.z, xrr[2]); v = v > 0.f ? v : NEG * v; p = fmaf(v, attv.z, p);
      v = xls[3] + fmaf(eav, wev.w, xrr[3]); v = v > 0.f ? v : NEG * v; p = fmaf(v, attv.w, p);
    }
    p += __shfl_xor(p, 1);
    p += __shfl_xor(p, 2);
    p += __shfl_xor(p, 4);
    // branchless online softmax
    float mn = fmaxf(m, p);
    float sc = __expf(m - mn);
    float ex = __expf(p - mn);
    den = fmaf(den, sc, ex);
#pragma unroll
    for (int c = 0; c < 4; c++) acc[c] = fmaf(acc[c], sc, ex * xls[c]);
    m = mn;
  }
  float rd = 1.f / den;
  float4 bv = *(const float4*)(bias + j0);
  float bb[4] = {bv.x, bv.y, bv.z, bv.w};
  short hi[4], lo[4];
#pragma unroll
  for (int c = 0; c < 4; c++) {
    float hv = tanhf(fmaf(acc[c], rd, bb[c]));
    unsigned short hb = f2bf(hv);
    hi[c] = (short)hb;
    lo[c] = (short)f2bf(hv - bf2f(hb));
  }
  *(short4v*)(ah + (size_t)node * 256 + j0) = *(short4v*)hi;
  *(short4v*)(al + (size_t)node * 256 + j0) = *(short4v*)lo;
}

// ---------- W2 = [wl2 | wr2] transposed to [n][k], split hi/lo ----------
__global__ void k_wsplit(const float* __restrict__ wl, const float* __restrict__ wr,
                         short* __restrict__ bh, short* __restrict__ bl) {
  int id = blockIdx.x * 256 + threadIdx.x;  // 65536
  int n = id >> 8, k = id & 255;
  float w = n < 128 ? wl[k * 128 + n] : wr[k * 128 + n - 128];
  unsigned short hb = f2bf(w);
  bh[n * 256 + k] = (short)hb;
  bl[n * 256 + k] = (short)f2bf(w - bf2f(hb));
}

// layer-2 GEMM: C = A(h1) @ W2, K=256, 3 bf16 passes (hi*hi + hi*lo + lo*hi).
// BM=128, BN=64, BK=32; 4 waves, wave tile 64x32. xl output stored fp16, xr f32.
__global__ __launch_bounds__(256) void k_gemm2(const short* __restrict__ ah,
                                               const short* __restrict__ al,
                                               const short* __restrict__ bh,
                                               const short* __restrict__ bl,
                                               _Float16* __restrict__ xlh,
                                               float* __restrict__ xr) {
  __shared__ short sA[128 * 40];
  __shared__ short sB[64 * 40];
  const int tid = threadIdx.x;
  const int bm = blockIdx.x >> 2, bn = blockIdx.x & 3;
  const int wid = tid >> 6, lane = tid & 63;
  const int wr = wid >> 1, wc = wid & 1;
  const int l15 = lane & 15, lhi = lane >> 4;
  const int srow = tid >> 2;
  const int kq = (tid & 3) * 8;
  f32x4 acc[4][2];
#pragma unroll
  for (int a = 0; a < 4; a++)
#pragma unroll
    for (int b = 0; b < 2; b++) acc[a][b] = (f32x4)(0.f);

  for (int p = 0; p < 3; p++) {
    const short* As = p < 2 ? ah : al;
    const short* Bs = p == 1 ? bl : bh;
#pragma unroll 1
    for (int st = 0; st < 8; st++) {
      const int k0 = st * 32;
      short8 va0 = *(const short8*)(As + ((long)(bm * 128 + srow) * 256 + k0 + kq));
      short8 va1 = *(const short8*)(As + ((long)(bm * 128 + 64 + srow) * 256 + k0 + kq));
      short8 vb  = *(const short8*)(Bs + ((long)(bn * 64 + srow) * 256 + k0 + kq));
      __syncthreads();
      *(short8*)&sA[srow * 40 + kq] = va0;
      *(short8*)&sA[(64 + srow) * 40 + kq] = va1;
      *(short8*)&sB[srow * 40 + kq] = vb;
      __syncthreads();
      short8 bfr[2];
#pragma unroll
      for (int fn = 0; fn < 2; fn++)
        bfr[fn] = *(const short8*)&sB[(wc * 32 + fn * 16 + l15) * 40 + lhi * 8];
#pragma unroll
      for (int fm = 0; fm < 4; fm++) {
        short8 afr = *(const short8*)&sA[(wr * 64 + fm * 16 + l15) * 40 + lhi * 8];
        acc[fm][0] = __builtin_amdgcn_mfma_f32_16x16x32_bf16(afr, bfr[0], acc[fm][0], 0, 0, 0);
        acc[fm][1] = __builtin_amdgcn_mfma_f32_16x16x32_bf16(afr, bfr[1], acc[fm][1], 0, 0, 0);
      }
    }
  }
#pragma unroll
  for (int fm = 0; fm < 4; fm++)
#pragma unroll
    for (int fn = 0; fn < 2; fn++) {
      int col = bn * 64 + wc * 32 + fn * 16 + l15;
#pragma unroll
      for (int j = 0; j < 4; j++) {
        int row = bm * 128 + wr * 64 + fm * 16 + lhi * 4 + j;
        if (col < 128) xlh[(long)row * 128 + col] = (_Float16)acc[fm][fn][j];
        else           xr[(long)row * 128 + col - 128] = acc[fm][fn][j];
      }
    }
}

// ---------- layer 2 gather: fp16 xl, O=128, H=8, C=16 ----------
__global__ __launch_bounds__(256) void k_gat2(const int* __restrict__ rowptr,
                                              const int* __restrict__ csrc,
                                              const float* __restrict__ ceav,
                                              const _Float16* __restrict__ xlh,
                                              const float* __restrict__ xr,
                                              const float* __restrict__ we,
                                              const float* __restrict__ att,
                                              const float* __restrict__ bias,
                                              float* __restrict__ hout) {
  const int lane = threadIdx.x & 63;
  const int node = blockIdx.x * 4 + (threadIdx.x >> 6);
  if (node >= NN) return;
  const int j0 = lane * 2;
  float2 xrr = *(const float2*)(xr + (long)node * 128 + j0);
  float2 wev = *(const float2*)(we + j0);
  float2 attv = *(const float2*)(att + j0);
  float m = -INFINITY, den = 0.f, acc0 = 0.f, acc1 = 0.f;
  const int kb = rowptr[node], ke = rowptr[node + 1];
  for (int k = kb; k < ke; k++) {
    const int s = csrc[k];
    const float eav = ceav[k];
    half2v a = *(const half2v*)(xlh + (long)s * 128 + j0);
    float av0 = (float)a.x, av1 = (float)a.y;
    float v0 = av0 + fmaf(eav, wev.x, xrr.x);
    float v1 = av1 + fmaf(eav, wev.y, xrr.y);
    v0 = v0 > 0.f ? v0 : NEG * v0;
    v1 = v1 > 0.f ? v1 : NEG * v1;
    float p = fmaf(v0, attv.x, v1 * attv.y);
    p += __shfl_xor(p, 1);
    p += __shfl_xor(p, 2);
    p += __shfl_xor(p, 4);
    float mn = fmaxf(m, p);
    float sc = __expf(m - mn);
    float ex = __expf(p - mn);
    den = fmaf(den, sc, ex);
    acc0 = fmaf(acc0, sc, ex * av0);
    acc1 = fmaf(acc1, sc, ex * av1);
    m = mn;
  }
  float rd = 1.f / den;
  hout[(long)node * 128 + j0]     = tanhf(fmaf(acc0, rd, bias[j0]));
  hout[(long)node * 128 + j0 + 1] = tanhf(fmaf(acc1, rd, bias[j0 + 1]));
}

// ---------- layer 3 transform (128 -> 8+8) ----------
__global__ void k_mm2_s(const float* __restrict__ h, int F, int O,
                        const float* __restrict__ wl, const float* __restrict__ wr,
                        float* __restrict__ xl, float* __restrict__ xr, int total) {
  int idx = blockIdx.x * 256 + threadIdx.x;
  if (idx >= total) return;
  int i = idx / 8, j = idx & 7;
  float al = 0.f, ar = 0.f;
  const float* hr = h + (size_t)i * F;
  for (int k = 0; k < F; k++) {
    float hv = hr[k];
    al = fmaf(hv, wl[k * O + j], al);
    ar = fmaf(hv, wr[k * O + j], ar);
  }
  xl[idx] = al;
  xr[idx] = ar;
}

// ---------- layer 3 gather: O=8, H=1, 8-lane group per node ----------
__global__ __launch_bounds__(256) void k_gat3(const int* __restrict__ rowptr,
                                              const int* __restrict__ csrc,
                                              const float* __restrict__ ceav,
                                              const float* __restrict__ xl,
                                              const float* __restrict__ xr,
                                              const float* __restrict__ we,
                                              const float* __restrict__ att,
                                              const float* __restrict__ bias,
                                              float* __restrict__ hout) {
  const int lane = threadIdx.x & 7;
  const int node = blockIdx.x * 32 + (threadIdx.x >> 3);
  if (node >= NN) return;
  const float xrr = xr[node * 8 + lane];
  const float wev = we[lane];
  const float attv = att[lane];
  float m = -INFINITY, den = 0.f, acc = 0.f;
  const int kb = rowptr[node], ke = rowptr[node + 1];
  for (int k = kb; k < ke; k++) {
    const int s = csrc[k];
    const float eav = ceav[k];
    const float av = xl[s * 8 + lane];
    float v = av + fmaf(eav, wev, xrr);
    v = v > 0.f ? v : NEG * v;
    float p = v * attv;
    p += __shfl_xor(p, 1);
    p += __shfl_xor(p, 2);
    p += __shfl_xor(p, 4);
    float mn = fmaxf(m, p);
    float sc = __expf(m - mn);
    float ex = __expf(p - mn);
    den = fmaf(den, sc, ex);
    acc = fmaf(acc, sc, ex * av);
    m = mn;
  }
  hout[node * 8 + lane] = tanhf(acc / den + bias[lane]);
}

// ---------- pooling + head ----------
__global__ void k_pool1(const int* __restrict__ bat, const float* __restrict__ h3,
                        float* __restrict__ sums, float* __restrict__ cnt) {
  int i = blockIdx.x * 256 + threadIdx.x;
  if (i < NN) {
    int b = bat[i];
    atomicAdd(cnt + b, 1.f);
#pragma unroll
    for (int j = 0; j < 8; j++) atomicAdd(sums + b * 8 + j, h3[(size_t)i * 8 + j]);
  }
}

__global__ void k_pool2(const float* __restrict__ sums, const float* __restrict__ cnt,
                        const float* __restrict__ w4, const float* __restrict__ b4,
                        float* __restrict__ out) {
  int b = blockIdx.x * 256 + threadIdx.x;
  if (b < NB) {
    float c = fmaxf(cnt[b], 1.f);
    float acc = b4[0];
#pragma unroll
    for (int j = 0; j < 8; j++) acc = fmaf(sums[b * 8 + j] / c, w4[j], acc);
    out[b] = acc;
  }
}

extern "C" void kernel_launch(void* const* d_in, const int* in_sizes, int n_in,
                              void* d_out, int out_size, void* d_ws, size_t ws_size,
                              hipStream_t stream) {
  const float* x   = (const float*)d_in[0];
  const int*   ei  = (const int*)d_in[1];
  const float* ea  = (const float*)d_in[2];
  const int*   bat = (const int*)d_in[3];
  const float* w0  = (const float*)d_in[4];
  const float* b0  = (const float*)d_in[5];
  const float* wl1 = (const float*)d_in[6];
  const float* wr1 = (const float*)d_in[7];
  const float* we1 = (const float*)d_in[8];
  const float* at1 = (const float*)d_in[9];
  const float* b1  = (const float*)d_in[10];
  const float* wl2 = (const float*)d_in[11];
  const float* wr2 = (const float*)d_in[12];
  const float* we2 = (const float*)d_in[13];
  const float* at2 = (const float*)d_in[14];
  const float* b2  = (const float*)d_in[15];
  const float* wl3 = (const float*)d_in[16];
  const float* wr3 = (const float*)d_in[17];
  const float* we3 = (const float*)d_in[18];
  const float* at3 = (const float*)d_in[19];
  const float* b3  = (const float*)d_in[20];
  const float* w4  = (const float*)d_in[21];
  const float* b4  = (const float*)d_in[22];
  float* out = (float*)d_out;

  char* W = (char*)d_ws;
  size_t o = 0;
  auto alloc = [&](size_t bytes) { void* p = W + o; o += (bytes + 255) & ~(size_t)255; return p; };
  int*      degi   = (int*)alloc(NN * 4);
  int*      fillc  = (int*)alloc(NN * 4);
  float*    lpa    = (float*)alloc(NN * 4);
  int*      rowptr = (int*)alloc((NN + 1) * 4);
  int*      pre    = (int*)alloc(NN * 4);
  int*      bsum   = (int*)alloc(256 * 4);
  int*      csrc   = (int*)alloc((size_t)NEF * 4);
  float*    ceav   = (float*)alloc((size_t)NEF * 4);
  float*    h0p    = (float*)alloc((size_t)8 * NN * 4);
  short*    Ah     = (short*)alloc((size_t)NNP * 256 * 2);
  short*    Al     = (short*)alloc((size_t)NNP * 256 * 2);
  short*    Bh     = (short*)alloc((size_t)256 * 256 * 2);
  short*    Bl     = (short*)alloc((size_t)256 * 256 * 2);
  _Float16* Xlh2   = (_Float16*)alloc((size_t)NNP * 128 * 2);
  float*    Xr2    = (float*)alloc((size_t)NNP * 128 * 4);
  float*    H2     = (float*)alloc((size_t)NN * 128 * 4);
  float*    Xl3    = (float*)alloc((size_t)NN * 8 * 4);
  float*    Xr3    = (float*)alloc((size_t)NN * 8 * 4);
  float*    H3     = (float*)alloc((size_t)NN * 8 * 4);
  float*    PS     = (float*)alloc(8 * NB * 4);
  float*    PC     = (float*)alloc(NB * 4);
  (void)ws_size; (void)in_sizes; (void)n_in; (void)out_size;

  const int NBLK = cdiv(NN, 256);

  // ---- CSR build ----
  hipMemsetAsync(degi, 0, NN * 4, stream);
  hipMemsetAsync(fillc, 0, NN * 4, stream);
  hipMemsetAsync(lpa, 0, NN * 4, stream);
  hipMemsetAsync(Ah + (size_t)NN * 256, 0, (size_t)(NNP - NN) * 256 * 2, stream);
  hipMemsetAsync(Al + (size_t)NN * 256, 0, (size_t)(NNP - NN) * 256 * 2, stream);
  k_deg<<<cdiv(NE, 256), 256, 0, stream>>>(ei, ea, degi, lpa);
  k_loop<<<NBLK, 256, 0, stream>>>(lpa, degi);
  k_scan1<<<NBLK, 256, 0, stream>>>(degi, pre, bsum);
  k_scan2<<<1, 256, 0, stream>>>(bsum, NBLK);
  k_scan3<<<NBLK, 256, 0, stream>>>(pre, bsum, rowptr);
  k_fill<<<cdiv(NEF, 256), 256, 0, stream>>>(ei, ea, lpa, rowptr, fillc, csrc, ceav);

  k_h0<<<NBLK, 256, 0, stream>>>(x, w0, b0, h0p);

  // ---- layer 1 (fused transform+gather, emits bf16 hi/lo h1) ----
  k_gat1<<<cdiv(NN, 4), 256, 0, stream>>>(rowptr, csrc, ceav, h0p, wl1, wr1, we1, at1, b1, Ah, Al);

  // ---- layer 2: MFMA GEMM + fp16 gather ----
  k_wsplit<<<256, 256, 0, stream>>>(wl2, wr2, Bh, Bl);
  k_gemm2<<<(NNP / 128) * 4, 256, 0, stream>>>(Ah, Al, Bh, Bl, Xlh2, Xr2);
  k_gat2<<<cdiv(NN, 4), 256, 0, stream>>>(rowptr, csrc, ceav, Xlh2, Xr2, we2, at2, b2, H2);

  // ---- layer 3 ----
  k_mm2_s<<<cdiv(8 * NN, 256), 256, 0, stream>>>(H2, 128, 8, wl3, wr3, Xl3, Xr3, 8 * NN);
  k_gat3<<<cdiv(NN, 32), 256, 0, stream>>>(rowptr, csrc, ceav, Xl3, Xr3, we3, at3, b3, H3);

  // ---- pooling + head ----
  hipMemsetAsync(PS, 0, 9 * NB * 4, stream);
  k_pool1<<<NBLK, 256, 0, stream>>>(bat, H3, PS, PC);
  k_pool2<<<cdiv(NB, 256), 256, 0, stream>>>(PS, PC, w4, b4, out);
}

// Round 5
// 361.406 us; speedup vs baseline: 36.2507x; 1.1824x over previous
//
#include <hip/hip_runtime.h>
#include <math.h>

#define NN 40000
#define NNP 40064              // NN padded to 128 for MFMA GEMM
#define NE 500000
#define NEF (NN + NE)
#define NB 512
#define NEG 0.2f

static inline int cdiv(int a, int b) { return (a + b - 1) / b; }

typedef __attribute__((ext_vector_type(8))) short short8;
typedef __attribute__((ext_vector_type(4))) short short4v;
typedef __attribute__((ext_vector_type(4))) float f32x4;
typedef __attribute__((ext_vector_type(2))) _Float16 half2v;

__device__ __forceinline__ unsigned short f2bf(float f) {
  unsigned u = __float_as_uint(f);
  unsigned r = (u + 0x7fffu + ((u >> 16) & 1u)) >> 16;
  return (unsigned short)r;
}
__device__ __forceinline__ float bf2f(unsigned short h) {
  return __uint_as_float((unsigned)h << 16);
}
__device__ __forceinline__ float lrelu(float v) {
  return fmaxf(v, NEG * v);   // NEG in (0,1): max(v, 0.2v) == leaky_relu(v)
}

// ---------- self-loop attr prep ----------
__global__ void k_deg(const int* __restrict__ ei, const float* __restrict__ ea,
                      int* __restrict__ degi, float* __restrict__ esum) {
  int e = blockIdx.x * 256 + threadIdx.x;
  if (e < NE) {
    int d = ei[NE + e];
    atomicAdd(degi + d, 1);
    atomicAdd(esum + d, ea[e]);
  }
}

// lpa finalize + self-loop degree bump + h0 embed (merged)
__global__ void k_prep(float* __restrict__ lpa, int* __restrict__ degi,
                       const float* __restrict__ x, const float* __restrict__ w0,
                       const float* __restrict__ b0, float* __restrict__ h0p) {
  int i = blockIdx.x * 256 + threadIdx.x;
  if (i < NN) {
    int dg = degi[i];
    lpa[i] = dg > 0 ? lpa[i] / (float)dg : 0.f;
    degi[i] = dg + 1;
    float x0 = x[4 * i];
    float* o = h0p + 8 * (size_t)i;
#pragma unroll
    for (int j = 0; j < 4; j++) o[j] = fmaf(x0, w0[j], b0[j]);
    o[4] = x[4 * i + 1];
    o[5] = x[4 * i + 2];
    o[6] = x[4 * i + 3];
    o[7] = 0.f;
  }
}

// ---------- prefix scan ----------
__global__ void k_scan1(const int* __restrict__ degi, int* __restrict__ pre,
                        int* __restrict__ bsum) {
  __shared__ int sh[256];
  int t = threadIdx.x, i = blockIdx.x * 256 + t;
  sh[t] = i < NN ? degi[i] : 0;
  __syncthreads();
  for (int st = 1; st < 256; st <<= 1) {
    int a = t >= st ? sh[t - st] : 0;
    __syncthreads();
    sh[t] += a;
    __syncthreads();
  }
  if (i < NN) pre[i] = sh[t];
  if (t == 255) bsum[blockIdx.x] = sh[255];
}

__global__ void k_scan2(int* __restrict__ bsum, int nb) {
  __shared__ int sh[256];
  int t = threadIdx.x;
  sh[t] = t < nb ? bsum[t] : 0;
  __syncthreads();
  for (int st = 1; st < 256; st <<= 1) {
    int a = t >= st ? sh[t - st] : 0;
    __syncthreads();
    sh[t] += a;
    __syncthreads();
  }
  if (t < nb) bsum[t] = sh[t];
}

__global__ void k_scan3(const int* __restrict__ pre, const int* __restrict__ bsum,
                        int* __restrict__ rowptr) {
  int i = blockIdx.x * 256 + threadIdx.x;
  if (i < NN) {
    int off = blockIdx.x > 0 ? bsum[blockIdx.x - 1] : 0;
    rowptr[i + 1] = pre[i] + off;
    if (i == 0) rowptr[0] = 0;
  }
}

__global__ void k_fill(const int* __restrict__ ei, const float* __restrict__ ea,
                       const float* __restrict__ lpa, const int* __restrict__ rowptr,
                       int* __restrict__ fillc, int* __restrict__ csrc,
                       float* __restrict__ ceav) {
  int e = blockIdx.x * 256 + threadIdx.x;
  if (e >= NEF) return;
  int s, d;
  float v;
  if (e < NE) { s = ei[e]; d = ei[NE + e]; v = ea[e]; }
  else        { s = e - NE; d = s; v = lpa[s]; }
  int pos = atomicAdd(fillc + d, 1);
  int idx = rowptr[d] + pos;
  csrc[idx] = s;
  ceav[idx] = v;
}

// ---------- layer 1 fully fused; wave-uniform node -> scalar loads ----------
__global__ __launch_bounds__(256) void k_gat1(const int* __restrict__ rowptr,
                                              const int* __restrict__ csrc,
                                              const float* __restrict__ ceav,
                                              const float* __restrict__ h0p,
                                              const float* __restrict__ wl,
                                              const float* __restrict__ wr,
                                              const float* __restrict__ we,
                                              const float* __restrict__ att,
                                              const float* __restrict__ bias,
                                              short* __restrict__ ah,
                                              short* __restrict__ al) {
  const int lane = threadIdx.x & 63;
  const int node = __builtin_amdgcn_readfirstlane(blockIdx.x * 4 + (threadIdx.x >> 6));
  if (node >= NN) return;
  const int j0 = lane * 4;

  float4 wev = *(const float4*)(we + j0);
  float4 attv = *(const float4*)(att + j0);
  float wlr[7][4];
#pragma unroll
  for (int k = 0; k < 7; k++) {
    float4 t = *(const float4*)(wl + k * 256 + j0);
    wlr[k][0] = t.x; wlr[k][1] = t.y; wlr[k][2] = t.z; wlr[k][3] = t.w;
  }
  // xr for this node (uniform row -> scalar loads)
  float xrr[4] = {0.f, 0.f, 0.f, 0.f};
  {
    float4 hd0 = *(const float4*)(h0p + (size_t)node * 8);
    float4 hd1 = *(const float4*)(h0p + (size_t)node * 8 + 4);
    float hn[7] = {hd0.x, hd0.y, hd0.z, hd0.w, hd1.x, hd1.y, hd1.z};
#pragma unroll
    for (int k = 0; k < 7; k++) {
      float4 t = *(const float4*)(wr + k * 256 + j0);
      xrr[0] = fmaf(hn[k], t.x, xrr[0]);
      xrr[1] = fmaf(hn[k], t.y, xrr[1]);
      xrr[2] = fmaf(hn[k], t.z, xrr[2]);
      xrr[3] = fmaf(hn[k], t.w, xrr[3]);
    }
  }

  float m = -INFINITY, den = 0.f;
  float acc[4] = {0.f, 0.f, 0.f, 0.f};
  const int kb = rowptr[node], ke = rowptr[node + 1];
  for (int k = kb; k < ke; k++) {
    const int s = csrc[k];       // uniform -> s_load
    const float eav = ceav[k];   // uniform -> s_load
    float4 a0 = *(const float4*)(h0p + (size_t)s * 8);      // uniform row
    float4 a1 = *(const float4*)(h0p + (size_t)s * 8 + 4);
    float hs[7] = {a0.x, a0.y, a0.z, a0.w, a1.x, a1.y, a1.z};
    float xls[4] = {0.f, 0.f, 0.f, 0.f};
#pragma unroll
    for (int kk = 0; kk < 7; kk++) {
      xls[0] = fmaf(hs[kk], wlr[kk][0], xls[0]);
      xls[1] = fmaf(hs[kk], wlr[kk][1], xls[1]);
      xls[2] = fmaf(hs[kk], wlr[kk][2], xls[2]);
      xls[3] = fmaf(hs[kk], wlr[kk][3], xls[3]);
    }
    float p = 0.f;
    p = fmaf(lrelu(xls[0] + fmaf(eav, wev.x, xrr[0])), attv.x, p);
    p = fmaf(lrelu(xls[1] + fmaf(eav, wev.y, xrr[1])), attv.y, p);
    p = fmaf(lrelu(xls[2] + fmaf(eav, wev.z, xrr[2])), attv.z, p);
    p = fmaf(lrelu(xls[3] + fmaf(eav, wev.w, xrr[3])), attv.w, p);
    p += __shfl_xor(p, 1);
    p += __shfl_xor(p, 2);
    p += __shfl_xor(p, 4);
    float mn = fmaxf(m, p);
    float sc = __expf(m - mn);
    float ex = __expf(p - mn);
    den = fmaf(den, sc, ex);
#pragma unroll
    for (int c = 0; c < 4; c++) acc[c] = fmaf(acc[c], sc, ex * xls[c]);
    m = mn;
  }
  float rd = 1.f / den;
  float4 bv = *(const float4*)(bias + j0);
  float bb[4] = {bv.x, bv.y, bv.z, bv.w};
  short hi[4], lo[4];
#pragma unroll
  for (int c = 0; c < 4; c++) {
    float hv = tanhf(fmaf(acc[c], rd, bb[c]));
    unsigned short hb = f2bf(hv);
    hi[c] = (short)hb;
    lo[c] = (short)f2bf(hv - bf2f(hb));
  }
  *(short4v*)(ah + (size_t)node * 256 + j0) = *(short4v*)hi;
  *(short4v*)(al + (size_t)node * 256 + j0) = *(short4v*)lo;
}

// ---------- W2 = [wl2 | wr2] transposed to [n][k], split hi/lo ----------
__global__ void k_wsplit(const float* __restrict__ wl, const float* __restrict__ wr,
                         short* __restrict__ bh, short* __restrict__ bl) {
  int id = blockIdx.x * 256 + threadIdx.x;  // 65536
  int n = id >> 8, k = id & 255;
  float w = n < 128 ? wl[k * 128 + n] : wr[k * 128 + n - 128];
  unsigned short hb = f2bf(w);
  bh[n * 256 + k] = (short)hb;
  bl[n * 256 + k] = (short)f2bf(w - bf2f(hb));
}

// layer-2 GEMM: C = A(h1) @ W2, K=256, 3 bf16 passes (hi*hi + hi*lo + lo*hi).
__global__ __launch_bounds__(256) void k_gemm2(const short* __restrict__ ah,
                                               const short* __restrict__ al,
                                               const short* __restrict__ bh,
                                               const short* __restrict__ bl,
                                               _Float16* __restrict__ xlh,
                                               float* __restrict__ xr) {
  __shared__ short sA[128 * 40];
  __shared__ short sB[64 * 40];
  const int tid = threadIdx.x;
  const int bm = blockIdx.x >> 2, bn = blockIdx.x & 3;
  const int wid = tid >> 6, lane = tid & 63;
  const int wr = wid >> 1, wc = wid & 1;
  const int l15 = lane & 15, lhi = lane >> 4;
  const int srow = tid >> 2;
  const int kq = (tid & 3) * 8;
  f32x4 acc[4][2];
#pragma unroll
  for (int a = 0; a < 4; a++)
#pragma unroll
    for (int b = 0; b < 2; b++) acc[a][b] = (f32x4)(0.f);

  for (int p = 0; p < 3; p++) {
    const short* As = p < 2 ? ah : al;
    const short* Bs = p == 1 ? bl : bh;
#pragma unroll 1
    for (int st = 0; st < 8; st++) {
      const int k0 = st * 32;
      short8 va0 = *(const short8*)(As + ((long)(bm * 128 + srow) * 256 + k0 + kq));
      short8 va1 = *(const short8*)(As + ((long)(bm * 128 + 64 + srow) * 256 + k0 + kq));
      short8 vb  = *(const short8*)(Bs + ((long)(bn * 64 + srow) * 256 + k0 + kq));
      __syncthreads();
      *(short8*)&sA[srow * 40 + kq] = va0;
      *(short8*)&sA[(64 + srow) * 40 + kq] = va1;
      *(short8*)&sB[srow * 40 + kq] = vb;
      __syncthreads();
      short8 bfr[2];
#pragma unroll
      for (int fn = 0; fn < 2; fn++)
        bfr[fn] = *(const short8*)&sB[(wc * 32 + fn * 16 + l15) * 40 + lhi * 8];
#pragma unroll
      for (int fm = 0; fm < 4; fm++) {
        short8 afr = *(const short8*)&sA[(wr * 64 + fm * 16 + l15) * 40 + lhi * 8];
        acc[fm][0] = __builtin_amdgcn_mfma_f32_16x16x32_bf16(afr, bfr[0], acc[fm][0], 0, 0, 0);
        acc[fm][1] = __builtin_amdgcn_mfma_f32_16x16x32_bf16(afr, bfr[1], acc[fm][1], 0, 0, 0);
      }
    }
  }
#pragma unroll
  for (int fm = 0; fm < 4; fm++)
#pragma unroll
    for (int fn = 0; fn < 2; fn++) {
      int col = bn * 64 + wc * 32 + fn * 16 + l15;
#pragma unroll
      for (int j = 0; j < 4; j++) {
        int row = bm * 128 + wr * 64 + fm * 16 + lhi * 4 + j;
        if (col < 128) xlh[(long)row * 128 + col] = (_Float16)acc[fm][fn][j];
        else           xr[(long)row * 128 + col - 128] = acc[fm][fn][j];
      }
    }
}

// ---------- layer 2 gather: fp16 xl, O=128; wave-uniform node ----------
__global__ __launch_bounds__(256) void k_gat2(const int* __restrict__ rowptr,
                                              const int* __restrict__ csrc,
                                              const float* __restrict__ ceav,
                                              const _Float16* __restrict__ xlh,
                                              const float* __restrict__ xr,
                                              const float* __restrict__ we,
                                              const float* __restrict__ att,
                                              const float* __restrict__ bias,
                                              float* __restrict__ hout) {
  const int lane = threadIdx.x & 63;
  const int node = __builtin_amdgcn_readfirstlane(blockIdx.x * 4 + (threadIdx.x >> 6));
  if (node >= NN) return;
  const int j0 = lane * 2;
  float2 xrr = *(const float2*)(xr + (long)node * 128 + j0);
  float2 wev = *(const float2*)(we + j0);
  float2 attv = *(const float2*)(att + j0);
  float m = -INFINITY, den = 0.f, acc0 = 0.f, acc1 = 0.f;
  const int kb = rowptr[node], ke = rowptr[node + 1];
  for (int k = kb; k < ke; k++) {
    const int s = csrc[k];       // s_load
    const float eav = ceav[k];   // s_load
    half2v a = *(const half2v*)(xlh + (long)s * 128 + j0);  // SGPR base + lane offset
    float av0 = (float)a.x, av1 = (float)a.y;
    float v0 = lrelu(av0 + fmaf(eav, wev.x, xrr.x));
    float v1 = lrelu(av1 + fmaf(eav, wev.y, xrr.y));
    float p = fmaf(v0, attv.x, v1 * attv.y);
    p += __shfl_xor(p, 1);
    p += __shfl_xor(p, 2);
    p += __shfl_xor(p, 4);
    float mn = fmaxf(m, p);
    float sc = __expf(m - mn);
    float ex = __expf(p - mn);
    den = fmaf(den, sc, ex);
    acc0 = fmaf(acc0, sc, ex * av0);
    acc1 = fmaf(acc1, sc, ex * av1);
    m = mn;
  }
  float rd = 1.f / den;
  hout[(long)node * 128 + j0]     = tanhf(fmaf(acc0, rd, bias[j0]));
  hout[(long)node * 128 + j0 + 1] = tanhf(fmaf(acc1, rd, bias[j0 + 1]));
}

// ---------- layer 3 transform: 64 nodes/block, LDS-staged ----------
__global__ __launch_bounds__(256) void k_mm3(const float* __restrict__ h,
                                             const float* __restrict__ wl,
                                             const float* __restrict__ wr,
                                             float* __restrict__ xl,
                                             float* __restrict__ xr) {
  __shared__ float srow[64 * 132];   // rows padded 128->132 (bank spread)
  __shared__ float lw[128 * 16];     // [k][16]: j<8 wl, j>=8 wr
  const int t = threadIdx.x;
  const int n0 = blockIdx.x * 64;
#pragma unroll
  for (int q = 0; q < 8; q++) {
    int gi = (t + q * 256) * 4;
    int row = gi >> 7, col = gi & 127;
    float4 v = *(const float4*)(h + (size_t)(n0 + row) * 128 + col);
    *(float4*)&srow[row * 132 + col] = v;
  }
#pragma unroll
  for (int q = 0; q < 8; q++) {
    int idx = t + q * 256;           // 0..2047
    int k = idx >> 4, j = idx & 15;
    lw[idx] = j < 8 ? wl[k * 8 + j] : wr[k * 8 + (j - 8)];
  }
  __syncthreads();
  const int nid = t >> 2, g = t & 3;
  float a0 = 0.f, a1 = 0.f, a2 = 0.f, a3 = 0.f;
  const float* rp = &srow[nid * 132];
  for (int k = 0; k < 128; k++) {
    float hv = rp[k];
    float4 w = *(const float4*)&lw[k * 16 + g * 4];
    a0 = fmaf(hv, w.x, a0);
    a1 = fmaf(hv, w.y, a1);
    a2 = fmaf(hv, w.z, a2);
    a3 = fmaf(hv, w.w, a3);
  }
  float4 r = {a0, a1, a2, a3};
  int node = n0 + nid;
  float* dst = (g & 2) ? xr : xl;
  *(float4*)(dst + node * 8 + (g & 1) * 4) = r;
}

// ---------- layer 3 gather: O=8, H=1, 8-lane group per node ----------
__global__ __launch_bounds__(256) void k_gat3(const int* __restrict__ rowptr,
                                              const int* __restrict__ csrc,
                                              const float* __restrict__ ceav,
                                              const float* __restrict__ xl,
                                              const float* __restrict__ xr,
                                              const float* __restrict__ we,
                                              const float* __restrict__ att,
                                              const float* __restrict__ bias,
                                              float* __restrict__ hout) {
  const int lane = threadIdx.x & 7;
  const int node = blockIdx.x * 32 + (threadIdx.x >> 3);
  if (node >= NN) return;
  const float xrr = xr[node * 8 + lane];
  const float wev = we[lane];
  const float attv = att[lane];
  float m = -INFINITY, den = 0.f, acc = 0.f;
  const int kb = rowptr[node], ke = rowptr[node + 1];
  for (int k = kb; k < ke; k++) {
    const int s = csrc[k];
    const float eav = ceav[k];
    const float av = xl[s * 8 + lane];
    float v = lrelu(av + fmaf(eav, wev, xrr));
    float p = v * attv;
    p += __shfl_xor(p, 1);
    p += __shfl_xor(p, 2);
    p += __shfl_xor(p, 4);
    float mn = fmaxf(m, p);
    float sc = __expf(m - mn);
    float ex = __expf(p - mn);
    den = fmaf(den, sc, ex);
    acc = fmaf(acc, sc, ex * av);
    m = mn;
  }
  hout[node * 8 + lane] = tanhf(acc / den + bias[lane]);
}

// ---------- pooling + head ----------
__global__ void k_pool1(const int* __restrict__ bat, const float* __restrict__ h3,
                        float* __restrict__ sums, float* __restrict__ cnt) {
  int i = blockIdx.x * 256 + threadIdx.x;
  if (i < NN) {
    int b = bat[i];
    atomicAdd(cnt + b, 1.f);
#pragma unroll
    for (int j = 0; j < 8; j++) atomicAdd(sums + b * 8 + j, h3[(size_t)i * 8 + j]);
  }
}

__global__ void k_pool2(const float* __restrict__ sums, const float* __restrict__ cnt,
                        const float* __restrict__ w4, const float* __restrict__ b4,
                        float* __restrict__ out) {
  int b = blockIdx.x * 256 + threadIdx.x;
  if (b < NB) {
    float c = fmaxf(cnt[b], 1.f);
    float acc = b4[0];
#pragma unroll
    for (int j = 0; j < 8; j++) acc = fmaf(sums[b * 8 + j] / c, w4[j], acc);
    out[b] = acc;
  }
}

extern "C" void kernel_launch(void* const* d_in, const int* in_sizes, int n_in,
                              void* d_out, int out_size, void* d_ws, size_t ws_size,
                              hipStream_t stream) {
  const float* x   = (const float*)d_in[0];
  const int*   ei  = (const int*)d_in[1];
  const float* ea  = (const float*)d_in[2];
  const int*   bat = (const int*)d_in[3];
  const float* w0  = (const float*)d_in[4];
  const float* b0  = (const float*)d_in[5];
  const float* wl1 = (const float*)d_in[6];
  const float* wr1 = (const float*)d_in[7];
  const float* we1 = (const float*)d_in[8];
  const float* at1 = (const float*)d_in[9];
  const float* b1  = (const float*)d_in[10];
  const float* wl2 = (const float*)d_in[11];
  const float* wr2 = (const float*)d_in[12];
  const float* we2 = (const float*)d_in[13];
  const float* at2 = (const float*)d_in[14];
  const float* b2  = (const float*)d_in[15];
  const float* wl3 = (const float*)d_in[16];
  const float* wr3 = (const float*)d_in[17];
  const float* we3 = (const float*)d_in[18];
  const float* at3 = (const float*)d_in[19];
  const float* b3  = (const float*)d_in[20];
  const float* w4  = (const float*)d_in[21];
  const float* b4  = (const float*)d_in[22];
  float* out = (float*)d_out;

  char* W = (char*)d_ws;
  size_t o = 0;
  auto alloc = [&](size_t bytes) { void* p = W + o; o += (bytes + 255) & ~(size_t)255; return p; };
  int*      degi   = (int*)alloc(NN * 4);
  int*      fillc  = (int*)alloc(NN * 4);
  float*    lpa    = (float*)alloc(NN * 4);
  int*      rowptr = (int*)alloc((NN + 1) * 4);
  int*      pre    = (int*)alloc(NN * 4);
  int*      bsum   = (int*)alloc(256 * 4);
  int*      csrc   = (int*)alloc((size_t)NEF * 4);
  float*    ceav   = (float*)alloc((size_t)NEF * 4);
  float*    h0p    = (float*)alloc((size_t)8 * NN * 4);
  short*    Ah     = (short*)alloc((size_t)NNP * 256 * 2);
  short*    Al     = (short*)alloc((size_t)NNP * 256 * 2);
  short*    Bh     = (short*)alloc((size_t)256 * 256 * 2);
  short*    Bl     = (short*)alloc((size_t)256 * 256 * 2);
  _Float16* Xlh2   = (_Float16*)alloc((size_t)NNP * 128 * 2);
  float*    Xr2    = (float*)alloc((size_t)NNP * 128 * 4);
  float*    H2     = (float*)alloc((size_t)NN * 128 * 4);
  float*    Xl3    = (float*)alloc((size_t)NN * 8 * 4);
  float*    Xr3    = (float*)alloc((size_t)NN * 8 * 4);
  float*    H3     = (float*)alloc((size_t)NN * 8 * 4);
  float*    PS     = (float*)alloc(8 * NB * 4);
  float*    PC     = (float*)alloc(NB * 4);
  (void)ws_size; (void)in_sizes; (void)n_in; (void)out_size;

  const int NBLK = cdiv(NN, 256);

  // ---- CSR build ----
  hipMemsetAsync(degi, 0, NN * 4, stream);
  hipMemsetAsync(fillc, 0, NN * 4, stream);
  hipMemsetAsync(lpa, 0, NN * 4, stream);
  hipMemsetAsync(Ah + (size_t)NN * 256, 0, (size_t)(NNP - NN) * 256 * 2, stream);
  hipMemsetAsync(Al + (size_t)NN * 256, 0, (size_t)(NNP - NN) * 256 * 2, stream);
  k_deg<<<cdiv(NE, 256), 256, 0, stream>>>(ei, ea, degi, lpa);
  k_prep<<<NBLK, 256, 0, stream>>>(lpa, degi, x, w0, b0, h0p);
  k_scan1<<<NBLK, 256, 0, stream>>>(degi, pre, bsum);
  k_scan2<<<1, 256, 0, stream>>>(bsum, NBLK);
  k_scan3<<<NBLK, 256, 0, stream>>>(pre, bsum, rowptr);
  k_fill<<<cdiv(NEF, 256), 256, 0, stream>>>(ei, ea, lpa, rowptr, fillc, csrc, ceav);

  // ---- layer 1 (fused transform+gather, emits bf16 hi/lo h1) ----
  k_gat1<<<cdiv(NN, 4), 256, 0, stream>>>(rowptr, csrc, ceav, h0p, wl1, wr1, we1, at1, b1, Ah, Al);

  // ---- layer 2: MFMA GEMM + fp16 gather ----
  k_wsplit<<<256, 256, 0, stream>>>(wl2, wr2, Bh, Bl);
  k_gemm2<<<(NNP / 128) * 4, 256, 0, stream>>>(Ah, Al, Bh, Bl, Xlh2, Xr2);
  k_gat2<<<cdiv(NN, 4), 256, 0, stream>>>(rowptr, csrc, ceav, Xlh2, Xr2, we2, at2, b2, H2);

  // ---- layer 3 ----
  k_mm3<<<NN / 64, 256, 0, stream>>>(H2, wl3, wr3, Xl3, Xr3);
  k_gat3<<<cdiv(NN, 32), 256, 0, stream>>>(rowptr, csrc, ceav, Xl3, Xr3, we3, at3, b3, H3);

  // ---- pooling + head ----
  hipMemsetAsync(PS, 0, 9 * NB * 4, stream);
  k_pool1<<<NBLK, 256, 0, stream>>>(bat, H3, PS, PC);
  k_pool2<<<cdiv(NB, 256), 256, 0, stream>>>(PS, PC, w4, b4, out);
}

// Round 6
// 344.703 us; speedup vs baseline: 38.0072x; 1.0485x over previous
//
#include <hip/hip_runtime.h>
#include <math.h>

#define NN 40000
#define NNP 40064              // NN padded to 128 for MFMA GEMM
#define NE 500000
#define NEF (NN + NE)
#define NB 512
#define NEG 0.2f

static inline int cdiv(int a, int b) { return (a + b - 1) / b; }

typedef __attribute__((ext_vector_type(8))) short short8;
typedef __attribute__((ext_vector_type(4))) short short4v;
typedef __attribute__((ext_vector_type(4))) float f32x4;
typedef __attribute__((ext_vector_type(2))) _Float16 half2v;

__device__ __forceinline__ unsigned short f2bf(float f) {
  unsigned u = __float_as_uint(f);
  unsigned r = (u + 0x7fffu + ((u >> 16) & 1u)) >> 16;
  return (unsigned short)r;
}
__device__ __forceinline__ float bf2f(unsigned short h) {
  return __uint_as_float((unsigned)h << 16);
}
__device__ __forceinline__ float lrelu(float v) {
  return fmaxf(v, NEG * v);   // NEG in (0,1): max(v, 0.2v) == leaky_relu(v)
}

// ---------- self-loop attr prep ----------
__global__ void k_deg(const int* __restrict__ ei, const float* __restrict__ ea,
                      int* __restrict__ degi, float* __restrict__ esum) {
  int e = blockIdx.x * 256 + threadIdx.x;
  if (e < NE) {
    int d = ei[NE + e];
    atomicAdd(degi + d, 1);
    atomicAdd(esum + d, ea[e]);
  }
}

// scan1 merged with lpa finalize + h0 embed (degi is not written; +1 applied in-scan)
__global__ void k_scanA(const int* __restrict__ degi, int* __restrict__ pre,
                        int* __restrict__ bsum, float* __restrict__ lpa,
                        const float* __restrict__ x, const float* __restrict__ w0,
                        const float* __restrict__ b0, float* __restrict__ h0p) {
  __shared__ int sh[256];
  int t = threadIdx.x, i = blockIdx.x * 256 + t;
  int dg = i < NN ? degi[i] : -1;
  sh[t] = i < NN ? dg + 1 : 0;   // +1 self loop
  if (i < NN) {
    lpa[i] = dg > 0 ? lpa[i] / (float)dg : 0.f;
    float x0 = x[4 * i];
    float* o = h0p + 8 * (size_t)i;
#pragma unroll
    for (int j = 0; j < 4; j++) o[j] = fmaf(x0, w0[j], b0[j]);
    o[4] = x[4 * i + 1];
    o[5] = x[4 * i + 2];
    o[6] = x[4 * i + 3];
    o[7] = 0.f;
  }
  __syncthreads();
  for (int st = 1; st < 256; st <<= 1) {
    int a = t >= st ? sh[t - st] : 0;
    __syncthreads();
    sh[t] += a;
    __syncthreads();
  }
  if (i < NN) pre[i] = sh[t];
  if (t == 255) bsum[blockIdx.x] = sh[255];
}

__global__ void k_scan2(int* __restrict__ bsum, int nb) {
  __shared__ int sh[256];
  int t = threadIdx.x;
  sh[t] = t < nb ? bsum[t] : 0;
  __syncthreads();
  for (int st = 1; st < 256; st <<= 1) {
    int a = t >= st ? sh[t - st] : 0;
    __syncthreads();
    sh[t] += a;
    __syncthreads();
  }
  if (t < nb) bsum[t] = sh[t];
}

__global__ void k_scan3(const int* __restrict__ pre, const int* __restrict__ bsum,
                        int* __restrict__ rowptr) {
  int i = blockIdx.x * 256 + threadIdx.x;
  if (i < NN) {
    int off = blockIdx.x > 0 ? bsum[blockIdx.x - 1] : 0;
    rowptr[i + 1] = pre[i] + off;
    if (i == 0) rowptr[0] = 0;
  }
}

__global__ void k_fill(const int* __restrict__ ei, const float* __restrict__ ea,
                       const float* __restrict__ lpa, const int* __restrict__ rowptr,
                       int* __restrict__ fillc, int* __restrict__ csrc,
                       float* __restrict__ ceav) {
  int e = blockIdx.x * 256 + threadIdx.x;
  if (e >= NEF) return;
  int s, d;
  float v;
  if (e < NE) { s = ei[e]; d = ei[NE + e]; v = ea[e]; }
  else        { s = e - NE; d = s; v = lpa[s]; }
  int pos = atomicAdd(fillc + d, 1);
  int idx = rowptr[d] + pos;
  csrc[idx] = s;
  ceav[idx] = v;
}

// ---------- layer 1 fully fused; wave-uniform node; defer-max softmax ----------
__global__ __launch_bounds__(256) void k_gat1(const int* __restrict__ rowptr,
                                              const int* __restrict__ csrc,
                                              const float* __restrict__ ceav,
                                              const float* __restrict__ h0p,
                                              const float* __restrict__ wl,
                                              const float* __restrict__ wr,
                                              const float* __restrict__ we,
                                              const float* __restrict__ att,
                                              const float* __restrict__ bias,
                                              short* __restrict__ ah,
                                              short* __restrict__ al) {
  const int lane = threadIdx.x & 63;
  const int node = __builtin_amdgcn_readfirstlane(blockIdx.x * 4 + (threadIdx.x >> 6));
  const int j0 = lane * 4;
  if (node >= NN) {  // zero GEMM pad rows (node < NNP by grid construction)
    short4v z = {0, 0, 0, 0};
    *(short4v*)(ah + (size_t)node * 256 + j0) = z;
    *(short4v*)(al + (size_t)node * 256 + j0) = z;
    return;
  }

  float4 wev = *(const float4*)(we + j0);
  float4 attv = *(const float4*)(att + j0);
  float wlr[7][4];
#pragma unroll
  for (int k = 0; k < 7; k++) {
    float4 t = *(const float4*)(wl + k * 256 + j0);
    wlr[k][0] = t.x; wlr[k][1] = t.y; wlr[k][2] = t.z; wlr[k][3] = t.w;
  }
  float xrr[4] = {0.f, 0.f, 0.f, 0.f};
  {
    float4 hd0 = *(const float4*)(h0p + (size_t)node * 8);
    float4 hd1 = *(const float4*)(h0p + (size_t)node * 8 + 4);
    float hn[7] = {hd0.x, hd0.y, hd0.z, hd0.w, hd1.x, hd1.y, hd1.z};
#pragma unroll
    for (int k = 0; k < 7; k++) {
      float4 t = *(const float4*)(wr + k * 256 + j0);
      xrr[0] = fmaf(hn[k], t.x, xrr[0]);
      xrr[1] = fmaf(hn[k], t.y, xrr[1]);
      xrr[2] = fmaf(hn[k], t.z, xrr[2]);
      xrr[3] = fmaf(hn[k], t.w, xrr[3]);
    }
  }

  float m = -INFINITY, den = 0.f;
  float acc[4] = {0.f, 0.f, 0.f, 0.f};
  const int kb = rowptr[node], ke = rowptr[node + 1];
#pragma unroll 2
  for (int k = kb; k < ke; k++) {
    const int s = csrc[k];       // uniform -> s_load
    const float eav = ceav[k];   // uniform -> s_load
    float4 a0 = *(const float4*)(h0p + (size_t)s * 8);
    float4 a1 = *(const float4*)(h0p + (size_t)s * 8 + 4);
    float hs[7] = {a0.x, a0.y, a0.z, a0.w, a1.x, a1.y, a1.z};
    float xls[4] = {0.f, 0.f, 0.f, 0.f};
#pragma unroll
    for (int kk = 0; kk < 7; kk++) {
      xls[0] = fmaf(hs[kk], wlr[kk][0], xls[0]);
      xls[1] = fmaf(hs[kk], wlr[kk][1], xls[1]);
      xls[2] = fmaf(hs[kk], wlr[kk][2], xls[2]);
      xls[3] = fmaf(hs[kk], wlr[kk][3], xls[3]);
    }
    float p = 0.f;
    p = fmaf(lrelu(xls[0] + fmaf(eav, wev.x, xrr[0])), attv.x, p);
    p = fmaf(lrelu(xls[1] + fmaf(eav, wev.y, xrr[1])), attv.y, p);
    p = fmaf(lrelu(xls[2] + fmaf(eav, wev.z, xrr[2])), attv.z, p);
    p = fmaf(lrelu(xls[3] + fmaf(eav, wev.w, xrr[3])), attv.w, p);
    p += __shfl_xor(p, 1);
    p += __shfl_xor(p, 2);
    p += __shfl_xor(p, 4);
    if (!__all(p <= m + 8.f)) {       // rare rescale (first edge + outliers)
      float mn = fmaxf(m, p);
      float sc = __expf(m - mn);      // exp(-inf)=0 on first edge
      den *= sc;
#pragma unroll
      for (int c = 0; c < 4; c++) acc[c] *= sc;
      m = mn;
    }
    float ex = __expf(p - m);         // bounded by e^8
    den += ex;
#pragma unroll
    for (int c = 0; c < 4; c++) acc[c] = fmaf(ex, xls[c], acc[c]);
  }
  float rd = 1.f / den;
  float4 bv = *(const float4*)(bias + j0);
  float bb[4] = {bv.x, bv.y, bv.z, bv.w};
  short hi[4], lo[4];
#pragma unroll
  for (int c = 0; c < 4; c++) {
    float hv = tanhf(fmaf(acc[c], rd, bb[c]));
    unsigned short hb = f2bf(hv);
    hi[c] = (short)hb;
    lo[c] = (short)f2bf(hv - bf2f(hb));
  }
  *(short4v*)(ah + (size_t)node * 256 + j0) = *(short4v*)hi;
  *(short4v*)(al + (size_t)node * 256 + j0) = *(short4v*)lo;
}

// ---------- W2 = [wl2 | wr2] transposed to [n][k], split hi/lo ----------
__global__ void k_wsplit(const float* __restrict__ wl, const float* __restrict__ wr,
                         short* __restrict__ bh, short* __restrict__ bl) {
  int id = blockIdx.x * 256 + threadIdx.x;  // 65536
  int n = id >> 8, k = id & 255;
  float w = n < 128 ? wl[k * 128 + n] : wr[k * 128 + n - 128];
  unsigned short hb = f2bf(w);
  bh[n * 256 + k] = (short)hb;
  bl[n * 256 + k] = (short)f2bf(w - bf2f(hb));
}

// layer-2 GEMM, single K-sweep: acc += Ah·Bh + Ah·Bl + Al·Bh per tile.
// BM=128, BN=64, BK=32; 4 waves, wave tile 64x32. xl output fp16, xr f32.
__global__ __launch_bounds__(256) void k_gemm2(const short* __restrict__ ah,
                                               const short* __restrict__ al,
                                               const short* __restrict__ bh,
                                               const short* __restrict__ bl,
                                               _Float16* __restrict__ xlh,
                                               float* __restrict__ xr) {
  __shared__ short sAh[128 * 40];
  __shared__ short sAl[128 * 40];
  __shared__ short sBh[64 * 40];
  __shared__ short sBl[64 * 40];
  const int tid = threadIdx.x;
  const int bm = blockIdx.x >> 2, bn = blockIdx.x & 3;
  const int wid = tid >> 6, lane = tid & 63;
  const int wr = wid >> 1, wc = wid & 1;
  const int l15 = lane & 15, lhi = lane >> 4;
  const int srow = tid >> 2;
  const int kq = (tid & 3) * 8;
  f32x4 acc[4][2];
#pragma unroll
  for (int a = 0; a < 4; a++)
#pragma unroll
    for (int b = 0; b < 2; b++) acc[a][b] = (f32x4)(0.f);

#pragma unroll 1
  for (int st = 0; st < 8; st++) {
    const int k0 = st * 32;
    const long aoff0 = (long)(bm * 128 + srow) * 256 + k0 + kq;
    const long aoff1 = aoff0 + 64 * 256;
    const long boff = (long)(bn * 64 + srow) * 256 + k0 + kq;
    short8 vah0 = *(const short8*)(ah + aoff0);
    short8 vah1 = *(const short8*)(ah + aoff1);
    short8 val0 = *(const short8*)(al + aoff0);
    short8 val1 = *(const short8*)(al + aoff1);
    short8 vbh  = *(const short8*)(bh + boff);
    short8 vbl  = *(const short8*)(bl + boff);
    __syncthreads();  // previous step's frag reads done
    *(short8*)&sAh[srow * 40 + kq] = vah0;
    *(short8*)&sAh[(64 + srow) * 40 + kq] = vah1;
    *(short8*)&sAl[srow * 40 + kq] = val0;
    *(short8*)&sAl[(64 + srow) * 40 + kq] = val1;
    *(short8*)&sBh[srow * 40 + kq] = vbh;
    *(short8*)&sBl[srow * 40 + kq] = vbl;
    __syncthreads();
    short8 bfh[2], bfl[2];
#pragma unroll
    for (int fn = 0; fn < 2; fn++) {
      bfh[fn] = *(const short8*)&sBh[(wc * 32 + fn * 16 + l15) * 40 + lhi * 8];
      bfl[fn] = *(const short8*)&sBl[(wc * 32 + fn * 16 + l15) * 40 + lhi * 8];
    }
#pragma unroll
    for (int fm = 0; fm < 4; fm++) {
      short8 afh = *(const short8*)&sAh[(wr * 64 + fm * 16 + l15) * 40 + lhi * 8];
      short8 afl = *(const short8*)&sAl[(wr * 64 + fm * 16 + l15) * 40 + lhi * 8];
      acc[fm][0] = __builtin_amdgcn_mfma_f32_16x16x32_bf16(afh, bfh[0], acc[fm][0], 0, 0, 0);
      acc[fm][1] = __builtin_amdgcn_mfma_f32_16x16x32_bf16(afh, bfh[1], acc[fm][1], 0, 0, 0);
      acc[fm][0] = __builtin_amdgcn_mfma_f32_16x16x32_bf16(afh, bfl[0], acc[fm][0], 0, 0, 0);
      acc[fm][1] = __builtin_amdgcn_mfma_f32_16x16x32_bf16(afh, bfl[1], acc[fm][1], 0, 0, 0);
      acc[fm][0] = __builtin_amdgcn_mfma_f32_16x16x32_bf16(afl, bfh[0], acc[fm][0], 0, 0, 0);
      acc[fm][1] = __builtin_amdgcn_mfma_f32_16x16x32_bf16(afl, bfh[1], acc[fm][1], 0, 0, 0);
    }
  }
#pragma unroll
  for (int fm = 0; fm < 4; fm++)
#pragma unroll
    for (int fn = 0; fn < 2; fn++) {
      int col = bn * 64 + wc * 32 + fn * 16 + l15;
#pragma unroll
      for (int j = 0; j < 4; j++) {
        int row = bm * 128 + wr * 64 + fm * 16 + lhi * 4 + j;
        if (col < 128) xlh[(long)row * 128 + col] = (_Float16)acc[fm][fn][j];
        else           xr[(long)row * 128 + col - 128] = acc[fm][fn][j];
      }
    }
}

// ---------- layer 2 gather: fp16 xl, O=128; wave-uniform node; defer-max ----------
__global__ __launch_bounds__(256) void k_gat2(const int* __restrict__ rowptr,
                                              const int* __restrict__ csrc,
                                              const float* __restrict__ ceav,
                                              const _Float16* __restrict__ xlh,
                                              const float* __restrict__ xr,
                                              const float* __restrict__ we,
                                              const float* __restrict__ att,
                                              const float* __restrict__ bias,
                                              float* __restrict__ hout) {
  const int lane = threadIdx.x & 63;
  const int node = __builtin_amdgcn_readfirstlane(blockIdx.x * 4 + (threadIdx.x >> 6));
  if (node >= NN) return;
  const int j0 = lane * 2;
  float2 xrr = *(const float2*)(xr + (long)node * 128 + j0);
  float2 wev = *(const float2*)(we + j0);
  float2 attv = *(const float2*)(att + j0);
  float m = -INFINITY, den = 0.f, acc0 = 0.f, acc1 = 0.f;
  const int kb = rowptr[node], ke = rowptr[node + 1];
#pragma unroll 2
  for (int k = kb; k < ke; k++) {
    const int s = csrc[k];
    const float eav = ceav[k];
    half2v a = *(const half2v*)(xlh + (long)s * 128 + j0);
    float av0 = (float)a.x, av1 = (float)a.y;
    float v0 = lrelu(av0 + fmaf(eav, wev.x, xrr.x));
    float v1 = lrelu(av1 + fmaf(eav, wev.y, xrr.y));
    float p = fmaf(v0, attv.x, v1 * attv.y);
    p += __shfl_xor(p, 1);
    p += __shfl_xor(p, 2);
    p += __shfl_xor(p, 4);
    if (!__all(p <= m + 8.f)) {
      float mn = fmaxf(m, p);
      float sc = __expf(m - mn);
      den *= sc;
      acc0 *= sc;
      acc1 *= sc;
      m = mn;
    }
    float ex = __expf(p - m);
    den += ex;
    acc0 = fmaf(ex, av0, acc0);
    acc1 = fmaf(ex, av1, acc1);
  }
  float rd = 1.f / den;
  hout[(long)node * 128 + j0]     = tanhf(fmaf(acc0, rd, bias[j0]));
  hout[(long)node * 128 + j0 + 1] = tanhf(fmaf(acc1, rd, bias[j0 + 1]));
}

// ---------- layer 3 transform: 64 nodes/block, LDS-staged ----------
__global__ __launch_bounds__(256) void k_mm3(const float* __restrict__ h,
                                             const float* __restrict__ wl,
                                             const float* __restrict__ wr,
                                             float* __restrict__ xl,
                                             float* __restrict__ xr) {
  __shared__ float srow[64 * 132];
  __shared__ float lw[128 * 16];
  const int t = threadIdx.x;
  const int n0 = blockIdx.x * 64;
#pragma unroll
  for (int q = 0; q < 8; q++) {
    int gi = (t + q * 256) * 4;
    int row = gi >> 7, col = gi & 127;
    float4 v = *(const float4*)(h + (size_t)(n0 + row) * 128 + col);
    *(float4*)&srow[row * 132 + col] = v;
  }
#pragma unroll
  for (int q = 0; q < 8; q++) {
    int idx = t + q * 256;
    int k = idx >> 4, j = idx & 15;
    lw[idx] = j < 8 ? wl[k * 8 + j] : wr[k * 8 + (j - 8)];
  }
  __syncthreads();
  const int nid = t >> 2, g = t & 3;
  float a0 = 0.f, a1 = 0.f, a2 = 0.f, a3 = 0.f;
  const float* rp = &srow[nid * 132];
  for (int k = 0; k < 128; k++) {
    float hv = rp[k];
    float4 w = *(const float4*)&lw[k * 16 + g * 4];
    a0 = fmaf(hv, w.x, a0);
    a1 = fmaf(hv, w.y, a1);
    a2 = fmaf(hv, w.z, a2);
    a3 = fmaf(hv, w.w, a3);
  }
  float4 r = {a0, a1, a2, a3};
  int node = n0 + nid;
  float* dst = (g & 2) ? xr : xl;
  *(float4*)(dst + node * 8 + (g & 1) * 4) = r;
}

// ---------- layer 3 gather: O=8, H=1, 8-lane group per node; defer-max ----------
__global__ __launch_bounds__(256) void k_gat3(const int* __restrict__ rowptr,
                                              const int* __restrict__ csrc,
                                              const float* __restrict__ ceav,
                                              const float* __restrict__ xl,
                                              const float* __restrict__ xr,
                                              const float* __restrict__ we,
                                              const float* __restrict__ att,
                                              const float* __restrict__ bias,
                                              float* __restrict__ hout) {
  const int lane = threadIdx.x & 7;
  const int node = blockIdx.x * 32 + (threadIdx.x >> 3);
  if (node >= NN) return;
  const float xrr = xr[node * 8 + lane];
  const float wev = we[lane];
  const float attv = att[lane];
  float m = -INFINITY, den = 0.f, acc = 0.f;
  const int kb = rowptr[node], ke = rowptr[node + 1];
  for (int k = kb; k < ke; k++) {
    const int s = csrc[k];
    const float eav = ceav[k];
    const float av = xl[s * 8 + lane];
    float v = lrelu(av + fmaf(eav, wev, xrr));
    float p = v * attv;
    p += __shfl_xor(p, 1);
    p += __shfl_xor(p, 2);
    p += __shfl_xor(p, 4);
    if (p > m + 8.f) {              // per-group branch (8-lane groups diverge anyway)
      float mn = fmaxf(m, p);
      float sc = __expf(m - mn);
      den *= sc;
      acc *= sc;
      m = mn;
    }
    float ex = __expf(p - m);
    den += ex;
    acc = fmaf(ex, av, acc);
  }
  hout[node * 8 + lane] = tanhf(acc / den + bias[lane]);
}

// ---------- pooling + head ----------
__global__ void k_pool1(const int* __restrict__ bat, const float* __restrict__ h3,
                        float* __restrict__ sums, float* __restrict__ cnt) {
  int i = blockIdx.x * 256 + threadIdx.x;
  if (i < NN) {
    int b = bat[i];
    atomicAdd(cnt + b, 1.f);
#pragma unroll
    for (int j = 0; j < 8; j++) atomicAdd(sums + b * 8 + j, h3[(size_t)i * 8 + j]);
  }
}

__global__ void k_pool2(const float* __restrict__ sums, const float* __restrict__ cnt,
                        const float* __restrict__ w4, const float* __restrict__ b4,
                        float* __restrict__ out) {
  int b = blockIdx.x * 256 + threadIdx.x;
  if (b < NB) {
    float c = fmaxf(cnt[b], 1.f);
    float acc = b4[0];
#pragma unroll
    for (int j = 0; j < 8; j++) acc = fmaf(sums[b * 8 + j] / c, w4[j], acc);
    out[b] = acc;
  }
}

extern "C" void kernel_launch(void* const* d_in, const int* in_sizes, int n_in,
                              void* d_out, int out_size, void* d_ws, size_t ws_size,
                              hipStream_t stream) {
  const float* x   = (const float*)d_in[0];
  const int*   ei  = (const int*)d_in[1];
  const float* ea  = (const float*)d_in[2];
  const int*   bat = (const int*)d_in[3];
  const float* w0  = (const float*)d_in[4];
  const float* b0  = (const float*)d_in[5];
  const float* wl1 = (const float*)d_in[6];
  const float* wr1 = (const float*)d_in[7];
  const float* we1 = (const float*)d_in[8];
  const float* at1 = (const float*)d_in[9];
  const float* b1  = (const float*)d_in[10];
  const float* wl2 = (const float*)d_in[11];
  const float* wr2 = (const float*)d_in[12];
  const float* we2 = (const float*)d_in[13];
  const float* at2 = (const float*)d_in[14];
  const float* b2  = (const float*)d_in[15];
  const float* wl3 = (const float*)d_in[16];
  const float* wr3 = (const float*)d_in[17];
  const float* we3 = (const float*)d_in[18];
  const float* at3 = (const float*)d_in[19];
  const float* b3  = (const float*)d_in[20];
  const float* w4  = (const float*)d_in[21];
  const float* b4  = (const float*)d_in[22];
  float* out = (float*)d_out;

  char* W = (char*)d_ws;
  size_t o = 0;
  auto alloc = [&](size_t bytes) { void* p = W + o; o += (bytes + 255) & ~(size_t)255; return p; };
  int*      degi   = (int*)alloc(NN * 4);   // degi/fillc/lpa contiguous (one memset)
  int*      fillc  = (int*)alloc(NN * 4);
  float*    lpa    = (float*)alloc(NN * 4);
  int*      rowptr = (int*)alloc((NN + 1) * 4);
  int*      pre    = (int*)alloc(NN * 4);
  int*      bsum   = (int*)alloc(256 * 4);
  int*      csrc   = (int*)alloc((size_t)NEF * 4);
  float*    ceav   = (float*)alloc((size_t)NEF * 4);
  float*    h0p    = (float*)alloc((size_t)8 * NN * 4);
  short*    Ah     = (short*)alloc((size_t)NNP * 256 * 2);
  short*    Al     = (short*)alloc((size_t)NNP * 256 * 2);
  short*    Bh     = (short*)alloc((size_t)256 * 256 * 2);
  short*    Bl     = (short*)alloc((size_t)256 * 256 * 2);
  _Float16* Xlh2   = (_Float16*)alloc((size_t)NNP * 128 * 2);
  float*    Xr2    = (float*)alloc((size_t)NNP * 128 * 4);
  float*    H2     = (float*)alloc((size_t)NN * 128 * 4);
  float*    Xl3    = (float*)alloc((size_t)NN * 8 * 4);
  float*    Xr3    = (float*)alloc((size_t)NN * 8 * 4);
  float*    H3     = (float*)alloc((size_t)NN * 8 * 4);
  float*    PS     = (float*)alloc(8 * NB * 4);
  float*    PC     = (float*)alloc(NB * 4);
  (void)ws_size; (void)in_sizes; (void)n_in; (void)out_size;

  const int NBLK = cdiv(NN, 256);

  // ---- CSR build ----
  hipMemsetAsync(degi, 0, 3 * NN * 4, stream);  // degi + fillc + lpa
  k_deg<<<cdiv(NE, 256), 256, 0, stream>>>(ei, ea, degi, lpa);
  k_scanA<<<NBLK, 256, 0, stream>>>(degi, pre, bsum, lpa, x, w0, b0, h0p);
  k_scan2<<<1, 256, 0, stream>>>(bsum, NBLK);
  k_scan3<<<NBLK, 256, 0, stream>>>(pre, bsum, rowptr);
  k_fill<<<cdiv(NEF, 256), 256, 0, stream>>>(ei, ea, lpa, rowptr, fillc, csrc, ceav);

  // ---- layer 1 (fused transform+gather, emits bf16 hi/lo h1; zeroes pad rows) ----
  k_gat1<<<NNP / 4, 256, 0, stream>>>(rowptr, csrc, ceav, h0p, wl1, wr1, we1, at1, b1, Ah, Al);

  // ---- layer 2: MFMA GEMM (single sweep) + fp16 gather ----
  k_wsplit<<<256, 256, 0, stream>>>(wl2, wr2, Bh, Bl);
  k_gemm2<<<(NNP / 128) * 4, 256, 0, stream>>>(Ah, Al, Bh, Bl, Xlh2, Xr2);
  k_gat2<<<cdiv(NN, 4), 256, 0, stream>>>(rowptr, csrc, ceav, Xlh2, Xr2, we2, at2, b2, H2);

  // ---- layer 3 ----
  k_mm3<<<NN / 64, 256, 0, stream>>>(H2, wl3, wr3, Xl3, Xr3);
  k_gat3<<<cdiv(NN, 32), 256, 0, stream>>>(rowptr, csrc, ceav, Xl3, Xr3, we3, at3, b3, H3);

  // ---- pooling + head ----
  hipMemsetAsync(PS, 0, 9 * NB * 4, stream);
  k_pool1<<<NBLK, 256, 0, stream>>>(bat, H3, PS, PC);
  k_pool2<<<cdiv(NB, 256), 256, 0, stream>>>(PS, PC, w4, b4, out);
}

// Round 7
// 320.236 us; speedup vs baseline: 40.9111x; 1.0764x over previous
//
#include <hip/hip_runtime.h>
#include <math.h>

#define NN 40000
#define NNP 40064              // NN padded to 128 for MFMA GEMM
#define NE 500000
#define NEF (NN + NE)
#define NB 512
#define NEG 0.2f

static inline int cdiv(int a, int b) { return (a + b - 1) / b; }

typedef __attribute__((ext_vector_type(8))) short short8;
typedef __attribute__((ext_vector_type(4))) short short4v;
typedef __attribute__((ext_vector_type(4))) float f32x4;
typedef __attribute__((ext_vector_type(2))) _Float16 half2v;

__device__ __forceinline__ unsigned short f2bf(float f) {
  unsigned u = __float_as_uint(f);
  unsigned r = (u + 0x7fffu + ((u >> 16) & 1u)) >> 16;
  return (unsigned short)r;
}
__device__ __forceinline__ float bf2f(unsigned short h) {
  return __uint_as_float((unsigned)h << 16);
}
__device__ __forceinline__ float lrelu(float v) {
  return fmaxf(v, NEG * v);   // NEG in (0,1): max(v, 0.2v) == leaky_relu(v)
}
// sum over each aligned 8-lane group, DPP only (no LDS latency):
// xor1 (quad_perm 1,0,3,2=0xB1), xor2 (quad_perm 2,3,0,1=0x4E), row_half_mirror (0x141)
__device__ __forceinline__ float red8(float p) {
  p += __uint_as_float((unsigned)__builtin_amdgcn_mov_dpp((int)__float_as_uint(p), 0xB1, 0xF, 0xF, true));
  p += __uint_as_float((unsigned)__builtin_amdgcn_mov_dpp((int)__float_as_uint(p), 0x4E, 0xF, 0xF, true));
  p += __uint_as_float((unsigned)__builtin_amdgcn_mov_dpp((int)__float_as_uint(p), 0x141, 0xF, 0xF, true));
  return p;
}

// ---------- self-loop attr prep ----------
__global__ void k_deg(const int* __restrict__ ei, const float* __restrict__ ea,
                      int* __restrict__ degi, float* __restrict__ esum) {
  int e = blockIdx.x * 256 + threadIdx.x;
  if (e < NE) {
    int d = ei[NE + e];
    atomicAdd(degi + d, 1);
    atomicAdd(esum + d, ea[e]);
  }
}

// scan1 merged with lpa finalize (+1 self loop applied in-scan)
__global__ void k_scanA(const int* __restrict__ degi, int* __restrict__ pre,
                        int* __restrict__ bsum, float* __restrict__ lpa) {
  __shared__ int sh[256];
  int t = threadIdx.x, i = blockIdx.x * 256 + t;
  int dg = i < NN ? degi[i] : -1;
  sh[t] = i < NN ? dg + 1 : 0;
  if (i < NN) lpa[i] = dg > 0 ? lpa[i] / (float)dg : 0.f;
  __syncthreads();
  for (int st = 1; st < 256; st <<= 1) {
    int a = t >= st ? sh[t - st] : 0;
    __syncthreads();
    sh[t] += a;
    __syncthreads();
  }
  if (i < NN) pre[i] = sh[t];
  if (t == 255) bsum[blockIdx.x] = sh[255];
}

__global__ void k_scan2(int* __restrict__ bsum, int nb) {
  __shared__ int sh[256];
  int t = threadIdx.x;
  sh[t] = t < nb ? bsum[t] : 0;
  __syncthreads();
  for (int st = 1; st < 256; st <<= 1) {
    int a = t >= st ? sh[t - st] : 0;
    __syncthreads();
    sh[t] += a;
    __syncthreads();
  }
  if (t < nb) bsum[t] = sh[t];
}

__global__ void k_scan3(const int* __restrict__ pre, const int* __restrict__ bsum,
                        int* __restrict__ rowptr) {
  int i = blockIdx.x * 256 + threadIdx.x;
  if (i < NN) {
    int off = blockIdx.x > 0 ? bsum[blockIdx.x - 1] : 0;
    rowptr[i + 1] = pre[i] + off;
    if (i == 0) rowptr[0] = 0;
  }
}

__global__ void k_fill(const int* __restrict__ ei, const float* __restrict__ ea,
                       const float* __restrict__ lpa, const int* __restrict__ rowptr,
                       int* __restrict__ fillc, int* __restrict__ csrc,
                       float* __restrict__ ceav) {
  int e = blockIdx.x * 256 + threadIdx.x;
  if (e >= NEF) return;
  int s, d;
  float v;
  if (e < NE) { s = ei[e]; d = ei[NE + e]; v = ea[e]; }
  else        { s = e - NE; d = s; v = lpa[s]; }
  int pos = atomicAdd(fillc + d, 1);
  int idx = rowptr[d] + pos;
  csrc[idx] = s;
  ceav[idx] = v;
}

// ---------- layer 1 fully fused, strength-reduced (F=7 rank-1 structure) ----------
// xls[c] = x0*u[c] + v[c] + x*wl4[c] + y*wl5[c] + z*wl6[c]
__global__ __launch_bounds__(256) void k_gat1(const int* __restrict__ rowptr,
                                              const int* __restrict__ csrc,
                                              const float* __restrict__ ceav,
                                              const float* __restrict__ xx,
                                              const float* __restrict__ w0,
                                              const float* __restrict__ b0,
                                              const float* __restrict__ wl,
                                              const float* __restrict__ wr,
                                              const float* __restrict__ we,
                                              const float* __restrict__ att,
                                              const float* __restrict__ bias,
                                              short* __restrict__ ah,
                                              short* __restrict__ al) {
  const int lane = threadIdx.x & 63;
  const int node = __builtin_amdgcn_readfirstlane(blockIdx.x * 4 + (threadIdx.x >> 6));
  const int j0 = lane * 4;
  if (node >= NN) {  // zero GEMM pad rows (node < NNP by grid construction)
    short4v z = {0, 0, 0, 0};
    *(short4v*)(ah + (size_t)node * 256 + j0) = z;
    *(short4v*)(al + (size_t)node * 256 + j0) = z;
    return;
  }

  float4 wev = *(const float4*)(we + j0);
  float4 attv = *(const float4*)(att + j0);
  float w0s[4] = {w0[0], w0[1], w0[2], w0[3]};
  float b0s[4] = {b0[0], b0[1], b0[2], b0[3]};
  // u,v from wl rows 0..3; keep wl rows 4..6
  float u[4] = {0.f, 0.f, 0.f, 0.f}, v[4] = {0.f, 0.f, 0.f, 0.f};
#pragma unroll
  for (int j = 0; j < 4; j++) {
    float4 t = *(const float4*)(wl + j * 256 + j0);
    float tt[4] = {t.x, t.y, t.z, t.w};
#pragma unroll
    for (int c = 0; c < 4; c++) {
      u[c] = fmaf(w0s[j], tt[c], u[c]);
      v[c] = fmaf(b0s[j], tt[c], v[c]);
    }
  }
  float4 wl4 = *(const float4*)(wl + 4 * 256 + j0);
  float4 wl5 = *(const float4*)(wl + 5 * 256 + j0);
  float4 wl6 = *(const float4*)(wl + 6 * 256 + j0);

  // xr for this node (wr full 7 rows, once)
  float xrr[4] = {0.f, 0.f, 0.f, 0.f};
  {
    float4 xv = *(const float4*)(xx + (size_t)node * 4);
    float hn[7] = {fmaf(xv.x, w0s[0], b0s[0]), fmaf(xv.x, w0s[1], b0s[1]),
                   fmaf(xv.x, w0s[2], b0s[2]), fmaf(xv.x, w0s[3], b0s[3]),
                   xv.y, xv.z, xv.w};
#pragma unroll
    for (int k = 0; k < 7; k++) {
      float4 t = *(const float4*)(wr + k * 256 + j0);
      xrr[0] = fmaf(hn[k], t.x, xrr[0]);
      xrr[1] = fmaf(hn[k], t.y, xrr[1]);
      xrr[2] = fmaf(hn[k], t.z, xrr[2]);
      xrr[3] = fmaf(hn[k], t.w, xrr[3]);
    }
  }

  float m = -INFINITY, den = 0.f;
  float acc[4] = {0.f, 0.f, 0.f, 0.f};
  const int kb = rowptr[node], ke = rowptr[node + 1];
  // 1-deep software pipeline: next edge's (s, eav, x-row) loads issued before compute
  int s = csrc[kb];
  float eav = ceav[kb];
  float4 xs = *(const float4*)(xx + (size_t)s * 4);
  for (int k = kb; k < ke; k++) {
    const int idx = (k + 1 < ke) ? k + 1 : k;
    const int s2 = csrc[idx];
    const float eav2 = ceav[idx];
    const float4 xs2 = *(const float4*)(xx + (size_t)s2 * 4);

    float xls[4];
#pragma unroll
    for (int c = 0; c < 4; c++) xls[c] = fmaf(xs.x, u[c], v[c]);
    xls[0] = fmaf(xs.y, wl4.x, xls[0]); xls[1] = fmaf(xs.y, wl4.y, xls[1]);
    xls[2] = fmaf(xs.y, wl4.z, xls[2]); xls[3] = fmaf(xs.y, wl4.w, xls[3]);
    xls[0] = fmaf(xs.z, wl5.x, xls[0]); xls[1] = fmaf(xs.z, wl5.y, xls[1]);
    xls[2] = fmaf(xs.z, wl5.z, xls[2]); xls[3] = fmaf(xs.z, wl5.w, xls[3]);
    xls[0] = fmaf(xs.w, wl6.x, xls[0]); xls[1] = fmaf(xs.w, wl6.y, xls[1]);
    xls[2] = fmaf(xs.w, wl6.z, xls[2]); xls[3] = fmaf(xs.w, wl6.w, xls[3]);

    float p = 0.f;
    p = fmaf(lrelu(xls[0] + fmaf(eav, wev.x, xrr[0])), attv.x, p);
    p = fmaf(lrelu(xls[1] + fmaf(eav, wev.y, xrr[1])), attv.y, p);
    p = fmaf(lrelu(xls[2] + fmaf(eav, wev.z, xrr[2])), attv.z, p);
    p = fmaf(lrelu(xls[3] + fmaf(eav, wev.w, xrr[3])), attv.w, p);
    p = red8(p);
    if (!__all(p <= m + 8.f)) {       // rare rescale (first edge + outliers)
      float mn = fmaxf(m, p);
      float sc = __expf(m - mn);      // exp(-inf)=0 on first edge
      den *= sc;
#pragma unroll
      for (int c = 0; c < 4; c++) acc[c] *= sc;
      m = mn;
    }
    float ex = __expf(p - m);         // bounded by e^8
    den += ex;
#pragma unroll
    for (int c = 0; c < 4; c++) acc[c] = fmaf(ex, xls[c], acc[c]);
    s = s2; eav = eav2; xs = xs2;
  }
  float rd = 1.f / den;
  float4 bv = *(const float4*)(bias + j0);
  float bb[4] = {bv.x, bv.y, bv.z, bv.w};
  short hi[4], lo[4];
#pragma unroll
  for (int c = 0; c < 4; c++) {
    float hv = tanhf(fmaf(acc[c], rd, bb[c]));
    unsigned short hb = f2bf(hv);
    hi[c] = (short)hb;
    lo[c] = (short)f2bf(hv - bf2f(hb));
  }
  *(short4v*)(ah + (size_t)node * 256 + j0) = *(short4v*)hi;
  *(short4v*)(al + (size_t)node * 256 + j0) = *(short4v*)lo;
}

// ---------- W2 = [wl2 | wr2] transposed to [n][k], split hi/lo ----------
__global__ void k_wsplit(const float* __restrict__ wl, const float* __restrict__ wr,
                         short* __restrict__ bh, short* __restrict__ bl) {
  int id = blockIdx.x * 256 + threadIdx.x;  // 65536
  int n = id >> 8, k = id & 255;
  float w = n < 128 ? wl[k * 128 + n] : wr[k * 128 + n - 128];
  unsigned short hb = f2bf(w);
  bh[n * 256 + k] = (short)hb;
  bl[n * 256 + k] = (short)f2bf(w - bf2f(hb));
}

// layer-2 GEMM, single K-sweep: acc += Ah·Bh + Ah·Bl + Al·Bh per tile.
__global__ __launch_bounds__(256) void k_gemm2(const short* __restrict__ ah,
                                               const short* __restrict__ al,
                                               const short* __restrict__ bh,
                                               const short* __restrict__ bl,
                                               _Float16* __restrict__ xlh,
                                               float* __restrict__ xr) {
  __shared__ short sAh[128 * 40];
  __shared__ short sAl[128 * 40];
  __shared__ short sBh[64 * 40];
  __shared__ short sBl[64 * 40];
  const int tid = threadIdx.x;
  const int bm = blockIdx.x >> 2, bn = blockIdx.x & 3;
  const int wid = tid >> 6, lane = tid & 63;
  const int wr = wid >> 1, wc = wid & 1;
  const int l15 = lane & 15, lhi = lane >> 4;
  const int srow = tid >> 2;
  const int kq = (tid & 3) * 8;
  f32x4 acc[4][2];
#pragma unroll
  for (int a = 0; a < 4; a++)
#pragma unroll
    for (int b = 0; b < 2; b++) acc[a][b] = (f32x4)(0.f);

#pragma unroll 1
  for (int st = 0; st < 8; st++) {
    const int k0 = st * 32;
    const long aoff0 = (long)(bm * 128 + srow) * 256 + k0 + kq;
    const long aoff1 = aoff0 + 64 * 256;
    const long boff = (long)(bn * 64 + srow) * 256 + k0 + kq;
    short8 vah0 = *(const short8*)(ah + aoff0);
    short8 vah1 = *(const short8*)(ah + aoff1);
    short8 val0 = *(const short8*)(al + aoff0);
    short8 val1 = *(const short8*)(al + aoff1);
    short8 vbh  = *(const short8*)(bh + boff);
    short8 vbl  = *(const short8*)(bl + boff);
    __syncthreads();
    *(short8*)&sAh[srow * 40 + kq] = vah0;
    *(short8*)&sAh[(64 + srow) * 40 + kq] = vah1;
    *(short8*)&sAl[srow * 40 + kq] = val0;
    *(short8*)&sAl[(64 + srow) * 40 + kq] = val1;
    *(short8*)&sBh[srow * 40 + kq] = vbh;
    *(short8*)&sBl[srow * 40 + kq] = vbl;
    __syncthreads();
    short8 bfh[2], bfl[2];
#pragma unroll
    for (int fn = 0; fn < 2; fn++) {
      bfh[fn] = *(const short8*)&sBh[(wc * 32 + fn * 16 + l15) * 40 + lhi * 8];
      bfl[fn] = *(const short8*)&sBl[(wc * 32 + fn * 16 + l15) * 40 + lhi * 8];
    }
#pragma unroll
    for (int fm = 0; fm < 4; fm++) {
      short8 afh = *(const short8*)&sAh[(wr * 64 + fm * 16 + l15) * 40 + lhi * 8];
      short8 afl = *(const short8*)&sAl[(wr * 64 + fm * 16 + l15) * 40 + lhi * 8];
      acc[fm][0] = __builtin_amdgcn_mfma_f32_16x16x32_bf16(afh, bfh[0], acc[fm][0], 0, 0, 0);
      acc[fm][1] = __builtin_amdgcn_mfma_f32_16x16x32_bf16(afh, bfh[1], acc[fm][1], 0, 0, 0);
      acc[fm][0] = __builtin_amdgcn_mfma_f32_16x16x32_bf16(afh, bfl[0], acc[fm][0], 0, 0, 0);
      acc[fm][1] = __builtin_amdgcn_mfma_f32_16x16x32_bf16(afh, bfl[1], acc[fm][1], 0, 0, 0);
      acc[fm][0] = __builtin_amdgcn_mfma_f32_16x16x32_bf16(afl, bfh[0], acc[fm][0], 0, 0, 0);
      acc[fm][1] = __builtin_amdgcn_mfma_f32_16x16x32_bf16(afl, bfh[1], acc[fm][1], 0, 0, 0);
    }
  }
#pragma unroll
  for (int fm = 0; fm < 4; fm++)
#pragma unroll
    for (int fn = 0; fn < 2; fn++) {
      int col = bn * 64 + wc * 32 + fn * 16 + l15;
#pragma unroll
      for (int j = 0; j < 4; j++) {
        int row = bm * 128 + wr * 64 + fm * 16 + lhi * 4 + j;
        if (col < 128) xlh[(long)row * 128 + col] = (_Float16)acc[fm][fn][j];
        else           xr[(long)row * 128 + col - 128] = acc[fm][fn][j];
      }
    }
}

// ---------- layer 2 gather: fp16 xl, O=128; pipelined; DPP reduce ----------
__global__ __launch_bounds__(256) void k_gat2(const int* __restrict__ rowptr,
                                              const int* __restrict__ csrc,
                                              const float* __restrict__ ceav,
                                              const _Float16* __restrict__ xlh,
                                              const float* __restrict__ xr,
                                              const float* __restrict__ we,
                                              const float* __restrict__ att,
                                              const float* __restrict__ bias,
                                              float* __restrict__ hout) {
  const int lane = threadIdx.x & 63;
  const int node = __builtin_amdgcn_readfirstlane(blockIdx.x * 4 + (threadIdx.x >> 6));
  if (node >= NN) return;
  const int j0 = lane * 2;
  float2 xrr = *(const float2*)(xr + (long)node * 128 + j0);
  float2 wev = *(const float2*)(we + j0);
  float2 attv = *(const float2*)(att + j0);
  float m = -INFINITY, den = 0.f, acc0 = 0.f, acc1 = 0.f;
  const int kb = rowptr[node], ke = rowptr[node + 1];
  int s = csrc[kb];
  float eav = ceav[kb];
  half2v a = *(const half2v*)(xlh + (long)s * 128 + j0);
  for (int k = kb; k < ke; k++) {
    const int idx = (k + 1 < ke) ? k + 1 : k;
    const int s2 = csrc[idx];
    const float eav2 = ceav[idx];
    const half2v a2 = *(const half2v*)(xlh + (long)s2 * 128 + j0);
    float av0 = (float)a.x, av1 = (float)a.y;
    float v0 = lrelu(av0 + fmaf(eav, wev.x, xrr.x));
    float v1 = lrelu(av1 + fmaf(eav, wev.y, xrr.y));
    float p = red8(fmaf(v0, attv.x, v1 * attv.y));
    if (!__all(p <= m + 8.f)) {
      float mn = fmaxf(m, p);
      float sc = __expf(m - mn);
      den *= sc;
      acc0 *= sc;
      acc1 *= sc;
      m = mn;
    }
    float ex = __expf(p - m);
    den += ex;
    acc0 = fmaf(ex, av0, acc0);
    acc1 = fmaf(ex, av1, acc1);
    s = s2; eav = eav2; a = a2;
  }
  float rd = 1.f / den;
  hout[(long)node * 128 + j0]     = tanhf(fmaf(acc0, rd, bias[j0]));
  hout[(long)node * 128 + j0 + 1] = tanhf(fmaf(acc1, rd, bias[j0 + 1]));
}

// ---------- layer 3 transform: 64 nodes/block, LDS-staged ----------
__global__ __launch_bounds__(256) void k_mm3(const float* __restrict__ h,
                                             const float* __restrict__ wl,
                                             const float* __restrict__ wr,
                                             float* __restrict__ xl,
                                             float* __restrict__ xr) {
  __shared__ float srow[64 * 132];
  __shared__ float lw[128 * 16];
  const int t = threadIdx.x;
  const int n0 = blockIdx.x * 64;
#pragma unroll
  for (int q = 0; q < 8; q++) {
    int gi = (t + q * 256) * 4;
    int row = gi >> 7, col = gi & 127;
    float4 v = *(const float4*)(h + (size_t)(n0 + row) * 128 + col);
    *(float4*)&srow[row * 132 + col] = v;
  }
#pragma unroll
  for (int q = 0; q < 8; q++) {
    int idx = t + q * 256;
    int k = idx >> 4, j = idx & 15;
    lw[idx] = j < 8 ? wl[k * 8 + j] : wr[k * 8 + (j - 8)];
  }
  __syncthreads();
  const int nid = t >> 2, g = t & 3;
  float a0 = 0.f, a1 = 0.f, a2 = 0.f, a3 = 0.f;
  const float* rp = &srow[nid * 132];
  for (int k = 0; k < 128; k++) {
    float hv = rp[k];
    float4 w = *(const float4*)&lw[k * 16 + g * 4];
    a0 = fmaf(hv, w.x, a0);
    a1 = fmaf(hv, w.y, a1);
    a2 = fmaf(hv, w.z, a2);
    a3 = fmaf(hv, w.w, a3);
  }
  float4 r = {a0, a1, a2, a3};
  int node = n0 + nid;
  float* dst = (g & 2) ? xr : xl;
  *(float4*)(dst + node * 8 + (g & 1) * 4) = r;
}

// ---------- layer 3 gather: O=8, H=1, 8-lane group per node; DPP reduce ----------
__global__ __launch_bounds__(256) void k_gat3(const int* __restrict__ rowptr,
                                              const int* __restrict__ csrc,
                                              const float* __restrict__ ceav,
                                              const float* __restrict__ xl,
                                              const float* __restrict__ xr,
                                              const float* __restrict__ we,
                                              const float* __restrict__ att,
                                              const float* __restrict__ bias,
                                              float* __restrict__ hout) {
  const int lane = threadIdx.x & 7;
  const int node = blockIdx.x * 32 + (threadIdx.x >> 3);
  if (node >= NN) return;
  const float xrr = xr[node * 8 + lane];
  const float wev = we[lane];
  const float attv = att[lane];
  float m = -INFINITY, den = 0.f, acc = 0.f;
  const int kb = rowptr[node], ke = rowptr[node + 1];
  for (int k = kb; k < ke; k++) {
    const int s = csrc[k];
    const float eav = ceav[k];
    const float av = xl[s * 8 + lane];
    float v = lrelu(av + fmaf(eav, wev, xrr));
    float p = red8(v * attv);
    if (p > m + 8.f) {
      float mn = fmaxf(m, p);
      float sc = __expf(m - mn);
      den *= sc;
      acc *= sc;
      m = mn;
    }
    float ex = __expf(p - m);
    den += ex;
    acc = fmaf(ex, av, acc);
  }
  hout[node * 8 + lane] = tanhf(acc / den + bias[lane]);
}

// ---------- pooling + head ----------
__global__ void k_pool1(const int* __restrict__ bat, const float* __restrict__ h3,
                        float* __restrict__ sums, float* __restrict__ cnt) {
  int i = blockIdx.x * 256 + threadIdx.x;
  if (i < NN) {
    int b = bat[i];
    atomicAdd(cnt + b, 1.f);
#pragma unroll
    for (int j = 0; j < 8; j++) atomicAdd(sums + b * 8 + j, h3[(size_t)i * 8 + j]);
  }
}

__global__ void k_pool2(const float* __restrict__ sums, const float* __restrict__ cnt,
                        const float* __restrict__ w4, const float* __restrict__ b4,
                        float* __restrict__ out) {
  int b = blockIdx.x * 256 + threadIdx.x;
  if (b < NB) {
    float c = fmaxf(cnt[b], 1.f);
    float acc = b4[0];
#pragma unroll
    for (int j = 0; j < 8; j++) acc = fmaf(sums[b * 8 + j] / c, w4[j], acc);
    out[b] = acc;
  }
}

extern "C" void kernel_launch(void* const* d_in, const int* in_sizes, int n_in,
                              void* d_out, int out_size, void* d_ws, size_t ws_size,
                              hipStream_t stream) {
  const float* x   = (const float*)d_in[0];
  const int*   ei  = (const int*)d_in[1];
  const float* ea  = (const float*)d_in[2];
  const int*   bat = (const int*)d_in[3];
  const float* w0  = (const float*)d_in[4];
  const float* b0  = (const float*)d_in[5];
  const float* wl1 = (const float*)d_in[6];
  const float* wr1 = (const float*)d_in[7];
  const float* we1 = (const float*)d_in[8];
  const float* at1 = (const float*)d_in[9];
  const float* b1  = (const float*)d_in[10];
  const float* wl2 = (const float*)d_in[11];
  const float* wr2 = (const float*)d_in[12];
  const float* we2 = (const float*)d_in[13];
  const float* at2 = (const float*)d_in[14];
  const float* b2  = (const float*)d_in[15];
  const float* wl3 = (const float*)d_in[16];
  const float* wr3 = (const float*)d_in[17];
  const float* we3 = (const float*)d_in[18];
  const float* at3 = (const float*)d_in[19];
  const float* b3  = (const float*)d_in[20];
  const float* w4  = (const float*)d_in[21];
  const float* b4  = (const float*)d_in[22];
  float* out = (float*)d_out;

  char* W = (char*)d_ws;
  size_t o = 0;
  auto alloc = [&](size_t bytes) { void* p = W + o; o += (bytes + 255) & ~(size_t)255; return p; };
  int*      degi   = (int*)alloc(NN * 4);   // degi/fillc/lpa contiguous (one memset)
  int*      fillc  = (int*)alloc(NN * 4);
  float*    lpa    = (float*)alloc(NN * 4);
  int*      rowptr = (int*)alloc((NN + 1) * 4);
  int*      pre    = (int*)alloc(NN * 4);
  int*      bsum   = (int*)alloc(256 * 4);
  int*      csrc   = (int*)alloc((size_t)NEF * 4);
  float*    ceav   = (float*)alloc((size_t)NEF * 4);
  short*    Ah     = (short*)alloc((size_t)NNP * 256 * 2);
  short*    Al     = (short*)alloc((size_t)NNP * 256 * 2);
  short*    Bh     = (short*)alloc((size_t)256 * 256 * 2);
  short*    Bl     = (short*)alloc((size_t)256 * 256 * 2);
  _Float16* Xlh2   = (_Float16*)alloc((size_t)NNP * 128 * 2);
  float*    Xr2    = (float*)alloc((size_t)NNP * 128 * 4);
  float*    H2     = (float*)alloc((size_t)NN * 128 * 4);
  float*    Xl3    = (float*)alloc((size_t)NN * 8 * 4);
  float*    Xr3    = (float*)alloc((size_t)NN * 8 * 4);
  float*    H3     = (float*)alloc((size_t)NN * 8 * 4);
  float*    PS     = (float*)alloc(8 * NB * 4);
  float*    PC     = (float*)alloc(NB * 4);
  (void)ws_size; (void)in_sizes; (void)n_in; (void)out_size;

  const int NBLK = cdiv(NN, 256);

  // ---- CSR build ----
  hipMemsetAsync(degi, 0, 3 * NN * 4, stream);  // degi + fillc + lpa
  k_deg<<<cdiv(NE, 256), 256, 0, stream>>>(ei, ea, degi, lpa);
  k_scanA<<<NBLK, 256, 0, stream>>>(degi, pre, bsum, lpa);
  k_scan2<<<1, 256, 0, stream>>>(bsum, NBLK);
  k_scan3<<<NBLK, 256, 0, stream>>>(pre, bsum, rowptr);
  k_fill<<<cdiv(NEF, 256), 256, 0, stream>>>(ei, ea, lpa, rowptr, fillc, csrc, ceav);

  // ---- layer 1 (fused transform+gather from raw x; emits bf16 hi/lo h1) ----
  k_gat1<<<NNP / 4, 256, 0, stream>>>(rowptr, csrc, ceav, x, w0, b0, wl1, wr1, we1, at1, b1, Ah, Al);

  // ---- layer 2: MFMA GEMM (single sweep) + fp16 gather ----
  k_wsplit<<<256, 256, 0, stream>>>(wl2, wr2, Bh, Bl);
  k_gemm2<<<(NNP / 128) * 4, 256, 0, stream>>>(Ah, Al, Bh, Bl, Xlh2, Xr2);
  k_gat2<<<cdiv(NN, 4), 256, 0, stream>>>(rowptr, csrc, ceav, Xlh2, Xr2, we2, at2, b2, H2);

  // ---- layer 3 ----
  k_mm3<<<NN / 64, 256, 0, stream>>>(H2, wl3, wr3, Xl3, Xr3);
  k_gat3<<<cdiv(NN, 32), 256, 0, stream>>>(rowptr, csrc, ceav, Xl3, Xr3, we3, at3, b3, H3);

  // ---- pooling + head ----
  hipMemsetAsync(PS, 0, 9 * NB * 4, stream);
  k_pool1<<<NBLK, 256, 0, stream>>>(bat, H3, PS, PC);
  k_pool2<<<cdiv(NB, 256), 256, 0, stream>>>(PS, PC, w4, b4, out);
}

// Round 8
// 256.532 us; speedup vs baseline: 51.0704x; 1.2483x over previous
//
#include <hip/hip_runtime.h>
#include <math.h>

#define NN 40000
#define NNP 40064              // NN padded to 128 for MFMA GEMM
#define NE 500000
#define NEF (NN + NE)
#define NB 512
#define NEG 0.2f

static inline int cdiv(int a, int b) { return (a + b - 1) / b; }

typedef __attribute__((ext_vector_type(8))) short short8;
typedef __attribute__((ext_vector_type(4))) short short4v;
typedef __attribute__((ext_vector_type(4))) float f32x4;
typedef __attribute__((ext_vector_type(2))) _Float16 half2v;

__device__ __forceinline__ unsigned short f2bf(float f) {
  unsigned u = __float_as_uint(f);
  unsigned r = (u + 0x7fffu + ((u >> 16) & 1u)) >> 16;
  return (unsigned short)r;
}
__device__ __forceinline__ float bf2f(unsigned short h) {
  return __uint_as_float((unsigned)h << 16);
}
__device__ __forceinline__ float lrelu(float v) {
  return fmaxf(v, NEG * v);   // NEG in (0,1): max(v, 0.2v) == leaky_relu(v)
}
// sum over each aligned 8-lane group, DPP only (no LDS latency):
__device__ __forceinline__ float red8(float p) {
  p += __uint_as_float((unsigned)__builtin_amdgcn_mov_dpp((int)__float_as_uint(p), 0xB1, 0xF, 0xF, true));
  p += __uint_as_float((unsigned)__builtin_amdgcn_mov_dpp((int)__float_as_uint(p), 0x4E, 0xF, 0xF, true));
  p += __uint_as_float((unsigned)__builtin_amdgcn_mov_dpp((int)__float_as_uint(p), 0x141, 0xF, 0xF, true));
  return p;
}

// ---------- self-loop attr prep ----------
__global__ void k_deg(const int* __restrict__ ei, const float* __restrict__ ea,
                      int* __restrict__ degi, float* __restrict__ esum) {
  int e = blockIdx.x * 256 + threadIdx.x;
  if (e < NE) {
    int d = ei[NE + e];
    atomicAdd(degi + d, 1);
    atomicAdd(esum + d, ea[e]);
  }
}

// scan1 merged with lpa finalize (+1 self loop applied in-scan)
__global__ void k_scanA(const int* __restrict__ degi, int* __restrict__ pre,
                        int* __restrict__ bsum, float* __restrict__ lpa) {
  __shared__ int sh[256];
  int t = threadIdx.x, i = blockIdx.x * 256 + t;
  int dg = i < NN ? degi[i] : -1;
  sh[t] = i < NN ? dg + 1 : 0;
  if (i < NN) lpa[i] = dg > 0 ? lpa[i] / (float)dg : 0.f;
  __syncthreads();
  for (int st = 1; st < 256; st <<= 1) {
    int a = t >= st ? sh[t - st] : 0;
    __syncthreads();
    sh[t] += a;
    __syncthreads();
  }
  if (i < NN) pre[i] = sh[t];
  if (t == 255) bsum[blockIdx.x] = sh[255];
}

__global__ void k_scan2(int* __restrict__ bsum, int nb) {
  __shared__ int sh[256];
  int t = threadIdx.x;
  sh[t] = t < nb ? bsum[t] : 0;
  __syncthreads();
  for (int st = 1; st < 256; st <<= 1) {
    int a = t >= st ? sh[t - st] : 0;
    __syncthreads();
    sh[t] += a;
    __syncthreads();
  }
  if (t < nb) bsum[t] = sh[t];
}

__global__ void k_scan3(const int* __restrict__ pre, const int* __restrict__ bsum,
                        int* __restrict__ rowptr) {
  int i = blockIdx.x * 256 + threadIdx.x;
  if (i < NN) {
    int off = blockIdx.x > 0 ? bsum[blockIdx.x - 1] : 0;
    rowptr[i + 1] = pre[i] + off;
    if (i == 0) rowptr[0] = 0;
  }
}

__global__ void k_fill(const int* __restrict__ ei, const float* __restrict__ ea,
                       const float* __restrict__ lpa, const int* __restrict__ rowptr,
                       int* __restrict__ fillc, int* __restrict__ csrc,
                       float* __restrict__ ceav) {
  int e = blockIdx.x * 256 + threadIdx.x;
  if (e >= NEF) return;
  int s, d;
  float v;
  if (e < NE) { s = ei[e]; d = ei[NE + e]; v = ea[e]; }
  else        { s = e - NE; d = s; v = lpa[s]; }
  int pos = atomicAdd(fillc + d, 1);
  int idx = rowptr[d] + pos;
  csrc[idx] = s;
  ceav[idx] = v;
}

// ---------- layer 1 fully fused, strength-reduced (F=7 rank-1 structure) ----------
__global__ __launch_bounds__(256) void k_gat1(const int* __restrict__ rowptr,
                                              const int* __restrict__ csrc,
                                              const float* __restrict__ ceav,
                                              const float* __restrict__ xx,
                                              const float* __restrict__ w0,
                                              const float* __restrict__ b0,
                                              const float* __restrict__ wl,
                                              const float* __restrict__ wr,
                                              const float* __restrict__ we,
                                              const float* __restrict__ att,
                                              const float* __restrict__ bias,
                                              short* __restrict__ ah,
                                              short* __restrict__ al) {
  const int lane = threadIdx.x & 63;
  const int node = __builtin_amdgcn_readfirstlane(blockIdx.x * 4 + (threadIdx.x >> 6));
  const int j0 = lane * 4;
  if (node >= NN) {  // zero GEMM pad rows (node < NNP by grid construction)
    short4v z = {0, 0, 0, 0};
    *(short4v*)(ah + (size_t)node * 256 + j0) = z;
    *(short4v*)(al + (size_t)node * 256 + j0) = z;
    return;
  }

  float4 wev = *(const float4*)(we + j0);
  float4 attv = *(const float4*)(att + j0);
  float w0s[4] = {w0[0], w0[1], w0[2], w0[3]};
  float b0s[4] = {b0[0], b0[1], b0[2], b0[3]};
  float u[4] = {0.f, 0.f, 0.f, 0.f}, v[4] = {0.f, 0.f, 0.f, 0.f};
#pragma unroll
  for (int j = 0; j < 4; j++) {
    float4 t = *(const float4*)(wl + j * 256 + j0);
    float tt[4] = {t.x, t.y, t.z, t.w};
#pragma unroll
    for (int c = 0; c < 4; c++) {
      u[c] = fmaf(w0s[j], tt[c], u[c]);
      v[c] = fmaf(b0s[j], tt[c], v[c]);
    }
  }
  float4 wl4 = *(const float4*)(wl + 4 * 256 + j0);
  float4 wl5 = *(const float4*)(wl + 5 * 256 + j0);
  float4 wl6 = *(const float4*)(wl + 6 * 256 + j0);

  float xrr[4] = {0.f, 0.f, 0.f, 0.f};
  {
    float4 xv = *(const float4*)(xx + (size_t)node * 4);
    float hn[7] = {fmaf(xv.x, w0s[0], b0s[0]), fmaf(xv.x, w0s[1], b0s[1]),
                   fmaf(xv.x, w0s[2], b0s[2]), fmaf(xv.x, w0s[3], b0s[3]),
                   xv.y, xv.z, xv.w};
#pragma unroll
    for (int k = 0; k < 7; k++) {
      float4 t = *(const float4*)(wr + k * 256 + j0);
      xrr[0] = fmaf(hn[k], t.x, xrr[0]);
      xrr[1] = fmaf(hn[k], t.y, xrr[1]);
      xrr[2] = fmaf(hn[k], t.z, xrr[2]);
      xrr[3] = fmaf(hn[k], t.w, xrr[3]);
    }
  }

  float m = -INFINITY, den = 0.f;
  float acc[4] = {0.f, 0.f, 0.f, 0.f};
  const int kb = rowptr[node], ke = rowptr[node + 1];
  int s = csrc[kb];
  float eav = ceav[kb];
  float4 xs = *(const float4*)(xx + (size_t)s * 4);
  for (int k = kb; k < ke; k++) {
    const int idx = (k + 1 < ke) ? k + 1 : k;
    const int s2 = csrc[idx];
    const float eav2 = ceav[idx];
    const float4 xs2 = *(const float4*)(xx + (size_t)s2 * 4);

    float xls[4];
#pragma unroll
    for (int c = 0; c < 4; c++) xls[c] = fmaf(xs.x, u[c], v[c]);
    xls[0] = fmaf(xs.y, wl4.x, xls[0]); xls[1] = fmaf(xs.y, wl4.y, xls[1]);
    xls[2] = fmaf(xs.y, wl4.z, xls[2]); xls[3] = fmaf(xs.y, wl4.w, xls[3]);
    xls[0] = fmaf(xs.z, wl5.x, xls[0]); xls[1] = fmaf(xs.z, wl5.y, xls[1]);
    xls[2] = fmaf(xs.z, wl5.z, xls[2]); xls[3] = fmaf(xs.z, wl5.w, xls[3]);
    xls[0] = fmaf(xs.w, wl6.x, xls[0]); xls[1] = fmaf(xs.w, wl6.y, xls[1]);
    xls[2] = fmaf(xs.w, wl6.z, xls[2]); xls[3] = fmaf(xs.w, wl6.w, xls[3]);

    float p = 0.f;
    p = fmaf(lrelu(xls[0] + fmaf(eav, wev.x, xrr[0])), attv.x, p);
    p = fmaf(lrelu(xls[1] + fmaf(eav, wev.y, xrr[1])), attv.y, p);
    p = fmaf(lrelu(xls[2] + fmaf(eav, wev.z, xrr[2])), attv.z, p);
    p = fmaf(lrelu(xls[3] + fmaf(eav, wev.w, xrr[3])), attv.w, p);
    p = red8(p);
    if (!__all(p <= m + 8.f)) {
      float mn = fmaxf(m, p);
      float sc = __expf(m - mn);
      den *= sc;
#pragma unroll
      for (int c = 0; c < 4; c++) acc[c] *= sc;
      m = mn;
    }
    float ex = __expf(p - m);
    den += ex;
#pragma unroll
    for (int c = 0; c < 4; c++) acc[c] = fmaf(ex, xls[c], acc[c]);
    s = s2; eav = eav2; xs = xs2;
  }
  float rd = 1.f / den;
  float4 bv = *(const float4*)(bias + j0);
  float bb[4] = {bv.x, bv.y, bv.z, bv.w};
  short hi[4], lo[4];
#pragma unroll
  for (int c = 0; c < 4; c++) {
    float hv = tanhf(fmaf(acc[c], rd, bb[c]));
    unsigned short hb = f2bf(hv);
    hi[c] = (short)hb;
    lo[c] = (short)f2bf(hv - bf2f(hb));
  }
  *(short4v*)(ah + (size_t)node * 256 + j0) = *(short4v*)hi;
  *(short4v*)(al + (size_t)node * 256 + j0) = *(short4v*)lo;
}

// ---------- W2 = [wl2 | wr2] transposed to [n][k], split hi/lo ----------
__global__ void k_wsplit(const float* __restrict__ wl, const float* __restrict__ wr,
                         short* __restrict__ bh, short* __restrict__ bl) {
  int id = blockIdx.x * 256 + threadIdx.x;  // 65536
  int n = id >> 8, k = id & 255;
  float w = n < 128 ? wl[k * 128 + n] : wr[k * 128 + n - 128];
  unsigned short hb = f2bf(w);
  bh[n * 256 + k] = (short)hb;
  bl[n * 256 + k] = (short)f2bf(w - bf2f(hb));
}

// layer-2 GEMM, single K-sweep: acc += Ah·Bh + Ah·Bl + Al·Bh per tile.
__global__ __launch_bounds__(256) void k_gemm2(const short* __restrict__ ah,
                                               const short* __restrict__ al,
                                               const short* __restrict__ bh,
                                               const short* __restrict__ bl,
                                               _Float16* __restrict__ xlh,
                                               float* __restrict__ xr) {
  __shared__ short sAh[128 * 40];
  __shared__ short sAl[128 * 40];
  __shared__ short sBh[64 * 40];
  __shared__ short sBl[64 * 40];
  const int tid = threadIdx.x;
  const int bm = blockIdx.x >> 2, bn = blockIdx.x & 3;
  const int wid = tid >> 6, lane = tid & 63;
  const int wr = wid >> 1, wc = wid & 1;
  const int l15 = lane & 15, lhi = lane >> 4;
  const int srow = tid >> 2;
  const int kq = (tid & 3) * 8;
  f32x4 acc[4][2];
#pragma unroll
  for (int a = 0; a < 4; a++)
#pragma unroll
    for (int b = 0; b < 2; b++) acc[a][b] = (f32x4)(0.f);

#pragma unroll 1
  for (int st = 0; st < 8; st++) {
    const int k0 = st * 32;
    const long aoff0 = (long)(bm * 128 + srow) * 256 + k0 + kq;
    const long aoff1 = aoff0 + 64 * 256;
    const long boff = (long)(bn * 64 + srow) * 256 + k0 + kq;
    short8 vah0 = *(const short8*)(ah + aoff0);
    short8 vah1 = *(const short8*)(ah + aoff1);
    short8 val0 = *(const short8*)(al + aoff0);
    short8 val1 = *(const short8*)(al + aoff1);
    short8 vbh  = *(const short8*)(bh + boff);
    short8 vbl  = *(const short8*)(bl + boff);
    __syncthreads();
    *(short8*)&sAh[srow * 40 + kq] = vah0;
    *(short8*)&sAh[(64 + srow) * 40 + kq] = vah1;
    *(short8*)&sAl[srow * 40 + kq] = val0;
    *(short8*)&sAl[(64 + srow) * 40 + kq] = val1;
    *(short8*)&sBh[srow * 40 + kq] = vbh;
    *(short8*)&sBl[srow * 40 + kq] = vbl;
    __syncthreads();
    short8 bfh[2], bfl[2];
#pragma unroll
    for (int fn = 0; fn < 2; fn++) {
      bfh[fn] = *(const short8*)&sBh[(wc * 32 + fn * 16 + l15) * 40 + lhi * 8];
      bfl[fn] = *(const short8*)&sBl[(wc * 32 + fn * 16 + l15) * 40 + lhi * 8];
    }
#pragma unroll
    for (int fm = 0; fm < 4; fm++) {
      short8 afh = *(const short8*)&sAh[(wr * 64 + fm * 16 + l15) * 40 + lhi * 8];
      short8 afl = *(const short8*)&sAl[(wr * 64 + fm * 16 + l15) * 40 + lhi * 8];
      acc[fm][0] = __builtin_amdgcn_mfma_f32_16x16x32_bf16(afh, bfh[0], acc[fm][0], 0, 0, 0);
      acc[fm][1] = __builtin_amdgcn_mfma_f32_16x16x32_bf16(afh, bfh[1], acc[fm][1], 0, 0, 0);
      acc[fm][0] = __builtin_amdgcn_mfma_f32_16x16x32_bf16(afh, bfl[0], acc[fm][0], 0, 0, 0);
      acc[fm][1] = __builtin_amdgcn_mfma_f32_16x16x32_bf16(afh, bfl[1], acc[fm][1], 0, 0, 0);
      acc[fm][0] = __builtin_amdgcn_mfma_f32_16x16x32_bf16(afl, bfh[0], acc[fm][0], 0, 0, 0);
      acc[fm][1] = __builtin_amdgcn_mfma_f32_16x16x32_bf16(afl, bfh[1], acc[fm][1], 0, 0, 0);
    }
  }
#pragma unroll
  for (int fm = 0; fm < 4; fm++)
#pragma unroll
    for (int fn = 0; fn < 2; fn++) {
      int col = bn * 64 + wc * 32 + fn * 16 + l15;
#pragma unroll
      for (int j = 0; j < 4; j++) {
        int row = bm * 128 + wr * 64 + fm * 16 + lhi * 4 + j;
        if (col < 128) xlh[(long)row * 128 + col] = (_Float16)acc[fm][fn][j];
        else           xr[(long)row * 128 + col - 128] = acc[fm][fn][j];
      }
    }
}

// ---------- layer 2 gather: fp16 xl, O=128; pipelined; DPP reduce ----------
__global__ __launch_bounds__(256) void k_gat2(const int* __restrict__ rowptr,
                                              const int* __restrict__ csrc,
                                              const float* __restrict__ ceav,
                                              const _Float16* __restrict__ xlh,
                                              const float* __restrict__ xr,
                                              const float* __restrict__ we,
                                              const float* __restrict__ att,
                                              const float* __restrict__ bias,
                                              float* __restrict__ hout) {
  const int lane = threadIdx.x & 63;
  const int node = __builtin_amdgcn_readfirstlane(blockIdx.x * 4 + (threadIdx.x >> 6));
  if (node >= NN) return;
  const int j0 = lane * 2;
  float2 xrr = *(const float2*)(xr + (long)node * 128 + j0);
  float2 wev = *(const float2*)(we + j0);
  float2 attv = *(const float2*)(att + j0);
  float m = -INFINITY, den = 0.f, acc0 = 0.f, acc1 = 0.f;
  const int kb = rowptr[node], ke = rowptr[node + 1];
  int s = csrc[kb];
  float eav = ceav[kb];
  half2v a = *(const half2v*)(xlh + (long)s * 128 + j0);
  for (int k = kb; k < ke; k++) {
    const int idx = (k + 1 < ke) ? k + 1 : k;
    const int s2 = csrc[idx];
    const float eav2 = ceav[idx];
    const half2v a2 = *(const half2v*)(xlh + (long)s2 * 128 + j0);
    float av0 = (float)a.x, av1 = (float)a.y;
    float v0 = lrelu(av0 + fmaf(eav, wev.x, xrr.x));
    float v1 = lrelu(av1 + fmaf(eav, wev.y, xrr.y));
    float p = red8(fmaf(v0, attv.x, v1 * attv.y));
    if (!__all(p <= m + 8.f)) {
      float mn = fmaxf(m, p);
      float sc = __expf(m - mn);
      den *= sc;
      acc0 *= sc;
      acc1 *= sc;
      m = mn;
    }
    float ex = __expf(p - m);
    den += ex;
    acc0 = fmaf(ex, av0, acc0);
    acc1 = fmaf(ex, av1, acc1);
    s = s2; eav = eav2; a = a2;
  }
  float rd = 1.f / den;
  hout[(long)node * 128 + j0]     = tanhf(fmaf(acc0, rd, bias[j0]));
  hout[(long)node * 128 + j0 + 1] = tanhf(fmaf(acc1, rd, bias[j0 + 1]));
}

// ---------- layer 3 transform: 64 nodes/block, LDS-staged ----------
__global__ __launch_bounds__(256) void k_mm3(const float* __restrict__ h,
                                             const float* __restrict__ wl,
                                             const float* __restrict__ wr,
                                             float* __restrict__ xl,
                                             float* __restrict__ xr) {
  __shared__ float srow[64 * 132];
  __shared__ float lw[128 * 16];
  const int t = threadIdx.x;
  const int n0 = blockIdx.x * 64;
#pragma unroll
  for (int q = 0; q < 8; q++) {
    int gi = (t + q * 256) * 4;
    int row = gi >> 7, col = gi & 127;
    float4 v = *(const float4*)(h + (size_t)(n0 + row) * 128 + col);
    *(float4*)&srow[row * 132 + col] = v;
  }
#pragma unroll
  for (int q = 0; q < 8; q++) {
    int idx = t + q * 256;
    int k = idx >> 4, j = idx & 15;
    lw[idx] = j < 8 ? wl[k * 8 + j] : wr[k * 8 + (j - 8)];
  }
  __syncthreads();
  const int nid = t >> 2, g = t & 3;
  float a0 = 0.f, a1 = 0.f, a2 = 0.f, a3 = 0.f;
  const float* rp = &srow[nid * 132];
  for (int k = 0; k < 128; k++) {
    float hv = rp[k];
    float4 w = *(const float4*)&lw[k * 16 + g * 4];
    a0 = fmaf(hv, w.x, a0);
    a1 = fmaf(hv, w.y, a1);
    a2 = fmaf(hv, w.z, a2);
    a3 = fmaf(hv, w.w, a3);
  }
  float4 r = {a0, a1, a2, a3};
  int node = n0 + nid;
  float* dst = (g & 2) ? xr : xl;
  *(float4*)(dst + node * 8 + (g & 1) * 4) = r;
}

// ---------- layer 3 gather: O=8, H=1, 8-lane group per node; DPP reduce ----------
__global__ __launch_bounds__(256) void k_gat3(const int* __restrict__ rowptr,
                                              const int* __restrict__ csrc,
                                              const float* __restrict__ ceav,
                                              const float* __restrict__ xl,
                                              const float* __restrict__ xr,
                                              const float* __restrict__ we,
                                              const float* __restrict__ att,
                                              const float* __restrict__ bias,
                                              float* __restrict__ hout) {
  const int lane = threadIdx.x & 7;
  const int node = blockIdx.x * 32 + (threadIdx.x >> 3);
  if (node >= NN) return;
  const float xrr = xr[node * 8 + lane];
  const float wev = we[lane];
  const float attv = att[lane];
  float m = -INFINITY, den = 0.f, acc = 0.f;
  const int kb = rowptr[node], ke = rowptr[node + 1];
  for (int k = kb; k < ke; k++) {
    const int s = csrc[k];
    const float eav = ceav[k];
    const float av = xl[s * 8 + lane];
    float v = lrelu(av + fmaf(eav, wev, xrr));
    float p = red8(v * attv);
    if (p > m + 8.f) {
      float mn = fmaxf(m, p);
      float sc = __expf(m - mn);
      den *= sc;
      acc *= sc;
      m = mn;
    }
    float ex = __expf(p - m);
    den += ex;
    acc = fmaf(ex, av, acc);
  }
  hout[node * 8 + lane] = tanhf(acc / den + bias[lane]);
}

// ---------- pooling: graph boundaries from sorted batch ----------
__global__ void k_gbound(const int* __restrict__ bat, int* __restrict__ gstart) {
  int i = blockIdx.x * 256 + threadIdx.x;
  if (i >= NN) return;
  int b = bat[i];
  int bp = i > 0 ? bat[i - 1] : -1;
  for (int g = bp + 1; g <= b; g++) gstart[g] = i;
  if (i == NN - 1)
    for (int g = b + 1; g <= NB; g++) gstart[g] = NN;
}

// one wave per graph: segmented mean-pool + head, no atomics.
// lane = (node_off 0..7)*8 + (ch 0..7)
__global__ __launch_bounds__(256) void k_poolG(const int* __restrict__ gstart,
                                               const float* __restrict__ h3,
                                               const float* __restrict__ w4,
                                               const float* __restrict__ b4,
                                               float* __restrict__ out) {
  const int lane = threadIdx.x & 63;
  const int g = blockIdx.x * 4 + (threadIdx.x >> 6);
  if (g >= NB) return;
  const int kb = gstart[g], ke = gstart[g + 1];
  const int ch = lane & 7, no = lane >> 3;
  float acc = 0.f;
  for (int n = kb + no; n < ke; n += 8)
    acc += h3[(size_t)n * 8 + ch];
  // fold the 8 node-groups (stride-8 lanes share ch)
  acc += __shfl_xor(acc, 8);
  acc += __shfl_xor(acc, 16);
  acc += __shfl_xor(acc, 32);
  float cnt = fmaxf((float)(ke - kb), 1.f);
  float yv = (acc / cnt) * w4[ch];
  yv = red8(yv);                      // sum 8 channels within lanes 0..7
  if (lane == 0) out[g] = yv + b4[0];
}

extern "C" void kernel_launch(void* const* d_in, const int* in_sizes, int n_in,
                              void* d_out, int out_size, void* d_ws, size_t ws_size,
                              hipStream_t stream) {
  const float* x   = (const float*)d_in[0];
  const int*   ei  = (const int*)d_in[1];
  const float* ea  = (const float*)d_in[2];
  const int*   bat = (const int*)d_in[3];
  const float* w0  = (const float*)d_in[4];
  const float* b0  = (const float*)d_in[5];
  const float* wl1 = (const float*)d_in[6];
  const float* wr1 = (const float*)d_in[7];
  const float* we1 = (const float*)d_in[8];
  const float* at1 = (const float*)d_in[9];
  const float* b1  = (const float*)d_in[10];
  const float* wl2 = (const float*)d_in[11];
  const float* wr2 = (const float*)d_in[12];
  const float* we2 = (const float*)d_in[13];
  const float* at2 = (const float*)d_in[14];
  const float* b2  = (const float*)d_in[15];
  const float* wl3 = (const float*)d_in[16];
  const float* wr3 = (const float*)d_in[17];
  const float* we3 = (const float*)d_in[18];
  const float* at3 = (const float*)d_in[19];
  const float* b3  = (const float*)d_in[20];
  const float* w4  = (const float*)d_in[21];
  const float* b4  = (const float*)d_in[22];
  float* out = (float*)d_out;

  char* W = (char*)d_ws;
  size_t o = 0;
  auto alloc = [&](size_t bytes) { void* p = W + o; o += (bytes + 255) & ~(size_t)255; return p; };
  int*      degi   = (int*)alloc(NN * 4);   // degi/fillc/lpa contiguous (one memset)
  int*      fillc  = (int*)alloc(NN * 4);
  float*    lpa    = (float*)alloc(NN * 4);
  int*      rowptr = (int*)alloc((NN + 1) * 4);
  int*      pre    = (int*)alloc(NN * 4);
  int*      bsum   = (int*)alloc(256 * 4);
  int*      gstart = (int*)alloc((NB + 1) * 4);
  int*      csrc   = (int*)alloc((size_t)NEF * 4);
  float*    ceav   = (float*)alloc((size_t)NEF * 4);
  short*    Ah     = (short*)alloc((size_t)NNP * 256 * 2);
  short*    Al     = (short*)alloc((size_t)NNP * 256 * 2);
  short*    Bh     = (short*)alloc((size_t)256 * 256 * 2);
  short*    Bl     = (short*)alloc((size_t)256 * 256 * 2);
  _Float16* Xlh2   = (_Float16*)alloc((size_t)NNP * 128 * 2);
  float*    Xr2    = (float*)alloc((size_t)NNP * 128 * 4);
  float*    H2     = (float*)alloc((size_t)NN * 128 * 4);
  float*    Xl3    = (float*)alloc((size_t)NN * 8 * 4);
  float*    Xr3    = (float*)alloc((size_t)NN * 8 * 4);
  float*    H3     = (float*)alloc((size_t)NN * 8 * 4);
  (void)ws_size; (void)in_sizes; (void)n_in; (void)out_size;

  const int NBLK = cdiv(NN, 256);

  // ---- CSR build ----
  hipMemsetAsync(degi, 0, 3 * NN * 4, stream);  // degi + fillc + lpa
  k_deg<<<cdiv(NE, 256), 256, 0, stream>>>(ei, ea, degi, lpa);
  k_scanA<<<NBLK, 256, 0, stream>>>(degi, pre, bsum, lpa);
  k_scan2<<<1, 256, 0, stream>>>(bsum, NBLK);
  k_scan3<<<NBLK, 256, 0, stream>>>(pre, bsum, rowptr);
  k_fill<<<cdiv(NEF, 256), 256, 0, stream>>>(ei, ea, lpa, rowptr, fillc, csrc, ceav);
  k_gbound<<<NBLK, 256, 0, stream>>>(bat, gstart);

  // ---- layer 1 (fused transform+gather from raw x; emits bf16 hi/lo h1) ----
  k_gat1<<<NNP / 4, 256, 0, stream>>>(rowptr, csrc, ceav, x, w0, b0, wl1, wr1, we1, at1, b1, Ah, Al);

  // ---- layer 2: MFMA GEMM (single sweep) + fp16 gather ----
  k_wsplit<<<256, 256, 0, stream>>>(wl2, wr2, Bh, Bl);
  k_gemm2<<<(NNP / 128) * 4, 256, 0, stream>>>(Ah, Al, Bh, Bl, Xlh2, Xr2);
  k_gat2<<<cdiv(NN, 4), 256, 0, stream>>>(rowptr, csrc, ceav, Xlh2, Xr2, we2, at2, b2, H2);

  // ---- layer 3 ----
  k_mm3<<<NN / 64, 256, 0, stream>>>(H2, wl3, wr3, Xl3, Xr3);
  k_gat3<<<cdiv(NN, 32), 256, 0, stream>>>(rowptr, csrc, ceav, Xl3, Xr3, we3, at3, b3, H3);

  // ---- pooling + head (segmented, no atomics) ----
  k_poolG<<<cdiv(NB, 4), 256, 0, stream>>>(gstart, H3, w4, b4, out);
}